// Round 1
// baseline (1214.734 us; speedup 1.0000x reference)
//
#include <hip/hip_runtime.h>

#define DEV __device__ __forceinline__

// ---------------- geometry ----------------
// x   [64,3,125,125]
// z1  [64,32,63,63]     conv1 3x3 s2 p1 + relu
// z2  [64,64,32,32]     conv2 3x3 s2 p1 + relu
// z3  [64,64,32,32]     conv3 1x1
// e   [64,64,32,32]     quantized (straight-through forward == q)
// h1  [64,64,64,64]     convT1 3x3 s2 p1 op1 + relu
// h2  [64,32,128,128]   convT2 3x3 s2 p1 op1 + relu
// xr  [64,3,125,125]    convT3 2x2 s1 p2

// ---------------- prep: weight transposes + codebook norms ----------------
// wc2 [ci32][kh][kw][co64]   from enc_w2 [co64][ci32][3][3]
// wc3 [ci64][co64]           from enc_w3 [co64][ci64]
// wt1 [ci64][kh][kw][co64]   from dec_w1 [ci64][co64][3][3]
// wt2 [ci64][kh][kw][co32]   from dec_w2 [ci64][co32][3][3]
// wt3 [ci32][kh2][kw2][4]    from dec_w3 [ci32][co3][2][2] (padded co->4)
// c2  [512]                  ||codebook_k||^2
__global__ __launch_bounds__(256) void k_prep(
    const float* __restrict__ ew2, const float* __restrict__ ew3,
    const float* __restrict__ dw1, const float* __restrict__ dw2,
    const float* __restrict__ dw3, const float* __restrict__ cb,
    float* __restrict__ wc2, float* __restrict__ wc3,
    float* __restrict__ wt1, float* __restrict__ wt2,
    float* __restrict__ wt3, float* __restrict__ c2) {
  int i = blockIdx.x * 256 + threadIdx.x;
  if (i < 18432) {
    int co = i & 63; int t = i >> 6; int kw = t % 3; t /= 3; int kh = t % 3; int ci = t / 3;
    wc2[i] = ew2[((co * 32 + ci) * 3 + kh) * 3 + kw];
  } else if (i < 22528) {
    int j = i - 18432; int co = j & 63; int ci = j >> 6;
    wc3[j] = ew3[co * 64 + ci];
  } else if (i < 59392) {
    int j = i - 22528; int co = j & 63; int t = j >> 6; int kw = t % 3; t /= 3; int kh = t % 3; int ci = t / 3;
    wt1[j] = dw1[((ci * 64 + co) * 3 + kh) * 3 + kw];
  } else if (i < 77824) {
    int j = i - 59392; int co = j & 31; int t = j >> 5; int kw = t % 3; t /= 3; int kh = t % 3; int ci = t / 3;
    wt2[j] = dw2[((ci * 32 + co) * 3 + kh) * 3 + kw];
  } else if (i < 78336) {
    int j = i - 77824; int co = j & 3; int t = j >> 2; int kw = t & 1; int kh = (t >> 1) & 1; int ci = t >> 2;
    wt3[j] = (co < 3) ? dw3[((ci * 3 + co) * 2 + kh) * 2 + kw] : 0.f;
  } else if (i < 78848) {
    int k = i - 78336;
    const float4* c4 = (const float4*)(cb + (k << 6));
    float s = 0.f;
    #pragma unroll
    for (int q = 0; q < 16; ++q) { float4 v = c4[q]; s += v.x*v.x + v.y*v.y + v.z*v.z + v.w*v.w; }
    c2[k] = s;
  }
}

// ---------------- conv1: direct, one output/thread ----------------
__global__ __launch_bounds__(256) void k_conv1(
    const float* __restrict__ x, const float* __restrict__ w,
    const float* __restrict__ bias, float* __restrict__ out) {
  int idx = blockIdx.x * 256 + threadIdx.x;          // [64,32,63,63] = 8128512
  int ow = idx % 63; int t = idx / 63;
  int oh = t % 63; t /= 63;
  int co = t & 31; int b = t >> 5;
  float acc = bias[co];
  const float* wp = w + co * 27;
  const float* xb = x + b * 3 * 125 * 125;
  int ih0 = 2 * oh - 1, iw0 = 2 * ow - 1;
  #pragma unroll
  for (int kh = 0; kh < 3; ++kh) {
    int ih = ih0 + kh;
    bool hok = (unsigned)ih < 125u;
    #pragma unroll
    for (int kw = 0; kw < 3; ++kw) {
      int iw = iw0 + kw;
      bool ok = hok && ((unsigned)iw < 125u);
      #pragma unroll
      for (int ci = 0; ci < 3; ++ci) {
        float v = ok ? xb[(ci * 125 + ih) * 125 + iw] : 0.f;
        acc = fmaf(v, wp[ci * 9 + kh * 3 + kw], acc);
      }
    }
  }
  out[idx] = fmaxf(acc, 0.f);
}

// ---------------- conv2: 8 co x 4 ow per thread ----------------
__global__ __launch_bounds__(256) void k_conv2(
    const float* __restrict__ in,   // z1 [64,32,63,63]
    const float* __restrict__ wt,   // wc2 [ci32][3][3][co64]
    const float* __restrict__ bias, float* __restrict__ out) { // z2 [64,64,32,32]
  int idx = blockIdx.x * 256 + threadIdx.x;  // 131072 threads
  int ow0 = (idx & 7) * 4;
  int oh  = (idx >> 3) & 31;
  int cog = (idx >> 8) & 7;
  int b   = idx >> 11;
  int co0 = cog * 8;
  float acc[8][4];
  #pragma unroll
  for (int j = 0; j < 8; ++j) {
    float bv = bias[co0 + j];
    #pragma unroll
    for (int s = 0; s < 4; ++s) acc[j][s] = bv;
  }
  int ih0 = 2 * oh - 1;
  for (int ci = 0; ci < 32; ++ci) {
    const float* ip = in + (b * 32 + ci) * 3969;
    const float* wc = wt + ci * 576;
    #pragma unroll
    for (int kh = 0; kh < 3; ++kh) {
      int ih = ih0 + kh;
      bool hok = (unsigned)ih < 63u;
      const float* rp = ip + ih * 63;
      #pragma unroll
      for (int kw = 0; kw < 3; ++kw) {
        float in4[4];
        #pragma unroll
        for (int s = 0; s < 4; ++s) {
          int iw = 2 * (ow0 + s) + kw - 1;
          in4[s] = (hok && ((unsigned)iw < 63u)) ? rp[iw] : 0.f;
        }
        const float* wp = wc + (kh * 3 + kw) * 64 + co0;
        float4 wlo = *(const float4*)wp;
        float4 whi = *(const float4*)(wp + 4);
        float wv[8] = {wlo.x, wlo.y, wlo.z, wlo.w, whi.x, whi.y, whi.z, whi.w};
        #pragma unroll
        for (int j = 0; j < 8; ++j)
          #pragma unroll
          for (int s = 0; s < 4; ++s) acc[j][s] = fmaf(in4[s], wv[j], acc[j][s]);
      }
    }
  }
  float* op = out + ((b * 64 + co0) * 32 + oh) * 32 + ow0;
  #pragma unroll
  for (int j = 0; j < 8; ++j) {
    float4 r = make_float4(fmaxf(acc[j][0], 0.f), fmaxf(acc[j][1], 0.f),
                           fmaxf(acc[j][2], 0.f), fmaxf(acc[j][3], 0.f));
    *(float4*)(op + j * 1024) = r;
  }
}

// ---------------- conv3 (1x1): 8 co x 4 px per thread ----------------
__global__ __launch_bounds__(256) void k_conv3(
    const float* __restrict__ in,   // z2 [64,64,1024]
    const float* __restrict__ wt,   // wc3 [ci64][co64]
    const float* __restrict__ bias, float* __restrict__ out) { // z3
  int idx = blockIdx.x * 256 + threadIdx.x;  // 131072
  int hw0 = (idx & 255) * 4;
  int cog = (idx >> 8) & 7;
  int b   = idx >> 11;
  int co0 = cog * 8;
  float acc[8][4];
  #pragma unroll
  for (int j = 0; j < 8; ++j) {
    float bv = bias[co0 + j];
    #pragma unroll
    for (int s = 0; s < 4; ++s) acc[j][s] = bv;
  }
  const float* ip = in + (b << 16) + hw0;
  for (int ci = 0; ci < 64; ++ci) {
    float4 v = *(const float4*)(ip + (ci << 10));
    const float* wp = wt + (ci << 6) + co0;
    float4 wlo = *(const float4*)wp;
    float4 whi = *(const float4*)(wp + 4);
    float wv[8] = {wlo.x, wlo.y, wlo.z, wlo.w, whi.x, whi.y, whi.z, whi.w};
    #pragma unroll
    for (int j = 0; j < 8; ++j) {
      acc[j][0] = fmaf(v.x, wv[j], acc[j][0]);
      acc[j][1] = fmaf(v.y, wv[j], acc[j][1]);
      acc[j][2] = fmaf(v.z, wv[j], acc[j][2]);
      acc[j][3] = fmaf(v.w, wv[j], acc[j][3]);
    }
  }
  float* op = out + ((b << 6) + co0) * 1024 + hw0;
  #pragma unroll
  for (int j = 0; j < 8; ++j)
    *(float4*)(op + (j << 10)) = make_float4(acc[j][0], acc[j][1], acc[j][2], acc[j][3]);
}

// ---------------- VQ: one pixel/thread ----------------
__global__ __launch_bounds__(256) void k_vq(
    const float* __restrict__ z3, const float* __restrict__ cb,
    const float* __restrict__ c2v, float* __restrict__ e,
    float* __restrict__ acc) {
  int n = blockIdx.x * 256 + threadIdx.x;  // 65536 pixels
  int b = n >> 10, hw = n & 1023;
  const float* zp = z3 + (b << 16) + hw;
  float z[64];
  #pragma unroll
  for (int d = 0; d < 64; ++d) z[d] = zp[d << 10];
  float best = 3.4e38f; int bi = 0;
  for (int k = 0; k < 512; ++k) {
    const float4* c4 = (const float4*)(cb + (k << 6));
    float d0 = 0.f, d1 = 0.f, d2 = 0.f, d3 = 0.f;
    #pragma unroll
    for (int i = 0; i < 16; ++i) {
      float4 c = c4[i];
      d0 = fmaf(z[4 * i + 0], c.x, d0);
      d1 = fmaf(z[4 * i + 1], c.y, d1);
      d2 = fmaf(z[4 * i + 2], c.z, d2);
      d3 = fmaf(z[4 * i + 3], c.w, d3);
    }
    float score = c2v[k] - 2.f * ((d0 + d1) + (d2 + d3));
    if (score < best) { best = score; bi = k; }
  }
  const float4* cq = (const float4*)(cb + (bi << 6));
  float* ep = e + (b << 16) + hw;
  float lsum = 0.f;
  #pragma unroll
  for (int i = 0; i < 16; ++i) {
    float4 c = cq[i];
    float df;
    ep[(4 * i + 0) << 10] = c.x; df = c.x - z[4 * i + 0]; lsum = fmaf(df, df, lsum);
    ep[(4 * i + 1) << 10] = c.y; df = c.y - z[4 * i + 1]; lsum = fmaf(df, df, lsum);
    ep[(4 * i + 2) << 10] = c.z; df = c.z - z[4 * i + 2]; lsum = fmaf(df, df, lsum);
    ep[(4 * i + 3) << 10] = c.w; df = c.w - z[4 * i + 3]; lsum = fmaf(df, df, lsum);
  }
  __shared__ float red[256];
  red[threadIdx.x] = lsum; __syncthreads();
  #pragma unroll
  for (int s = 128; s > 0; s >>= 1) {
    if (threadIdx.x < s) red[threadIdx.x] += red[threadIdx.x + s];
    __syncthreads();
  }
  if (threadIdx.x == 0) atomicAdd(acc + 0, red[0]);
}

// ---------------- convT row helper (3 kw taps, parity-exact) ----------------
// Thread owns 4 consecutive ow (ow0 even). For each kw, exactly 2 of the 4
// outputs are parity-valid (compile-time known). v0,v1,v2 = input row at
// x0, x0+1, x0+2.
template <int WIN, int COUT>
DEV void trow(const float* __restrict__ rp, bool hv,
              const float* __restrict__ wkh, int co0, int x0,
              float acc[8][4]) {
  float v0 = hv ? rp[x0] : 0.f;
  float v1 = hv ? rp[x0 + 1] : 0.f;
  float v2 = (hv && (x0 + 2 < WIN)) ? rp[x0 + 2] : 0.f;
  #pragma unroll
  for (int kw = 0; kw < 3; ++kw) {
    const float* wp = wkh + kw * COUT + co0;
    float4 wlo = *(const float4*)wp;
    float4 whi = *(const float4*)(wp + 4);
    float wv[8] = {wlo.x, wlo.y, wlo.z, wlo.w, whi.x, whi.y, whi.z, whi.w};
    const int sA = (kw == 1) ? 0 : 1;      // valid output slots: {sA, sA+2}
    const float vA = (kw == 0) ? v1 : v0;
    const float vB = (kw == 0) ? v2 : v1;
    #pragma unroll
    for (int j = 0; j < 8; ++j) {
      acc[j][sA]     = fmaf(vA, wv[j], acc[j][sA]);
      acc[j][sA + 2] = fmaf(vB, wv[j], acc[j][sA + 2]);
    }
  }
}

// ---------------- convT1: 64->64, 32x32 -> 64x64 ----------------
__global__ __launch_bounds__(256) void k_convT1(
    const float* __restrict__ in,   // e [64,64,32,32]
    const float* __restrict__ wt,   // wt1 [ci64][3][3][co64]
    const float* __restrict__ bias, float* __restrict__ out) { // h1
  int idx = blockIdx.x * 256 + threadIdx.x;  // 524288
  int owg = idx & 15, bl = (idx >> 4) & 3, oh = (idx >> 6) & 63;
  int cog = (idx >> 12) & 7, bh = idx >> 15;
  int b = bh * 4 + bl, co0 = cog * 8, ow0 = owg * 4, x0 = ow0 >> 1, y = oh >> 1;
  float acc[8][4];
  #pragma unroll
  for (int j = 0; j < 8; ++j) {
    float bv = bias[co0 + j];
    #pragma unroll
    for (int s = 0; s < 4; ++s) acc[j][s] = bv;
  }
  const float* inb = in + (b << 16);
  if ((oh & 1) == 0) {            // kh=1 only, ih=y  (wave-uniform branch)
    for (int ci = 0; ci < 64; ++ci)
      trow<32, 64>(inb + (ci << 10) + (y << 5), true, wt + ci * 576 + 192, co0, x0, acc);
  } else {                        // kh=0 (ih=y+1, mask), kh=2 (ih=y)
    bool hv = (y + 1) < 32;
    for (int ci = 0; ci < 64; ++ci) {
      const float* ip = inb + (ci << 10);
      const float* wci = wt + ci * 576;
      trow<32, 64>(ip + ((y + 1) << 5), hv, wci, co0, x0, acc);
      trow<32, 64>(ip + (y << 5), true, wci + 384, co0, x0, acc);
    }
  }
  float* op = out + (((b << 6) + co0) << 12) + (oh << 6) + ow0;
  #pragma unroll
  for (int j = 0; j < 8; ++j) {
    float4 r = make_float4(fmaxf(acc[j][0], 0.f), fmaxf(acc[j][1], 0.f),
                           fmaxf(acc[j][2], 0.f), fmaxf(acc[j][3], 0.f));
    *(float4*)(op + (j << 12)) = r;
  }
}

// ---------------- convT2: 64->32, 64x64 -> 128x128 ----------------
__global__ __launch_bounds__(256) void k_convT2(
    const float* __restrict__ in,   // h1 [64,64,64,64]
    const float* __restrict__ wt,   // wt2 [ci64][3][3][co32]
    const float* __restrict__ bias, float* __restrict__ out) { // h2
  int idx = blockIdx.x * 256 + threadIdx.x;  // 1048576
  int owg = idx & 31, bl = (idx >> 5) & 1, oh = (idx >> 6) & 127;
  int cog = (idx >> 13) & 3, bh = idx >> 15;
  int b = bh * 2 + bl, co0 = cog * 8, ow0 = owg * 4, x0 = ow0 >> 1, y = oh >> 1;
  float acc[8][4];
  #pragma unroll
  for (int j = 0; j < 8; ++j) {
    float bv = bias[co0 + j];
    #pragma unroll
    for (int s = 0; s < 4; ++s) acc[j][s] = bv;
  }
  const float* inb = in + (b << 18);
  if ((oh & 1) == 0) {
    for (int ci = 0; ci < 64; ++ci)
      trow<64, 32>(inb + (ci << 12) + (y << 6), true, wt + ci * 288 + 96, co0, x0, acc);
  } else {
    bool hv = (y + 1) < 64;
    for (int ci = 0; ci < 64; ++ci) {
      const float* ip = inb + (ci << 12);
      const float* wci = wt + ci * 288;
      trow<64, 32>(ip + ((y + 1) << 6), hv, wci, co0, x0, acc);
      trow<64, 32>(ip + (y << 6), true, wci + 192, co0, x0, acc);
    }
  }
  float* op = out + (((b << 5) + co0) << 14) + (oh << 7) + ow0;
  #pragma unroll
  for (int j = 0; j < 8; ++j) {
    float4 r = make_float4(fmaxf(acc[j][0], 0.f), fmaxf(acc[j][1], 0.f),
                           fmaxf(acc[j][2], 0.f), fmaxf(acc[j][3], 0.f));
    *(float4*)(op + (j << 14)) = r;
  }
}

// ---------------- convT3 + recon loss ----------------
__global__ __launch_bounds__(256) void k_convT3(
    const float* __restrict__ in,   // h2 [64,32,128,128]
    const float* __restrict__ wt,   // wt3 [ci32][2][2][4]
    const float* __restrict__ bias, const float* __restrict__ x,
    float* __restrict__ xr,         // d_out + 3
    float* __restrict__ acc) {
  int idx = blockIdx.x * 256 + threadIdx.x;  // 1,000,000 valid
  bool valid = idx < 1000000;
  float lsum = 0.f;
  if (valid) {
    int b = idx / 15625; int pix = idx - b * 15625;
    int oh = pix / 125;  int ow = pix - oh * 125;
    float a0 = bias[0], a1 = bias[1], a2 = bias[2];
    const float* inb = in + b * 524288;
    const float4* w4 = (const float4*)wt;
    for (int ci = 0; ci < 32; ++ci) {
      const float* ip = inb + (ci << 14);
      #pragma unroll
      for (int kh = 0; kh < 2; ++kh) {
        const float* rp = ip + ((oh + 2 - kh) << 7);
        #pragma unroll
        for (int kw = 0; kw < 2; ++kw) {
          float v = rp[ow + 2 - kw];
          float4 w = w4[(ci * 2 + kh) * 2 + kw];
          a0 = fmaf(v, w.x, a0);
          a1 = fmaf(v, w.y, a1);
          a2 = fmaf(v, w.z, a2);
        }
      }
    }
    int o = b * 46875 + pix;
    xr[o] = a0; xr[o + 15625] = a1; xr[o + 31250] = a2;
    float d0 = a0 - x[o], d1 = a1 - x[o + 15625], d2 = a2 - x[o + 31250];
    lsum = d0 * d0 + d1 * d1 + d2 * d2;
  }
  __shared__ float red[256];
  red[threadIdx.x] = lsum; __syncthreads();
  #pragma unroll
  for (int s = 128; s > 0; s >>= 1) {
    if (threadIdx.x < s) red[threadIdx.x] += red[threadIdx.x + s];
    __syncthreads();
  }
  if (threadIdx.x == 0) atomicAdd(acc + 1, red[0]);
}

// ---------------- finalize ----------------
__global__ void k_fin(const float* __restrict__ acc, float* __restrict__ out) {
  if (threadIdx.x == 0 && blockIdx.x == 0) {
    float eq  = 1.25f * acc[0] / 4194304.0f;  // (1+BETA)*MSE over [64,32,32,64]
    float rec = acc[1];
    out[0] = eq + rec;
    out[1] = eq;
    out[2] = rec;
  }
}

extern "C" void kernel_launch(void* const* d_in, const int* in_sizes, int n_in,
                              void* d_out, int out_size, void* d_ws, size_t ws_size,
                              hipStream_t stream) {
  (void)in_sizes; (void)n_in; (void)out_size; (void)ws_size;
  const float* x   = (const float*)d_in[0];
  const float* ew1 = (const float*)d_in[1];
  const float* eb1 = (const float*)d_in[2];
  const float* ew2 = (const float*)d_in[3];
  const float* eb2 = (const float*)d_in[4];
  const float* ew3 = (const float*)d_in[5];
  const float* eb3 = (const float*)d_in[6];
  const float* cb  = (const float*)d_in[7];
  const float* dw1 = (const float*)d_in[8];
  const float* db1 = (const float*)d_in[9];
  const float* dw2 = (const float*)d_in[10];
  const float* db2 = (const float*)d_in[11];
  const float* dw3 = (const float*)d_in[12];
  const float* db3 = (const float*)d_in[13];
  float* out = (float*)d_out;
  char*  ws  = (char*)d_ws;

  float* acc = (float*)(ws + 0);          // [0]=vq_sum [1]=recon_sum
  float* c2  = (float*)(ws + 256);
  float* wc2 = (float*)(ws + 4096);
  float* wc3 = (float*)(ws + 77824);
  float* wt1 = (float*)(ws + 94208);
  float* wt2 = (float*)(ws + 241664);
  float* wt3 = (float*)(ws + 315392);
  // big-region reuse: z1/z2/z3/e live in R1 and are dead before h2 (== R1) is
  // written by convT2. h1 is disjoint. Total ws use ~202 MB.
  float* z1  = (float*)(ws + 524288);
  float* z2  = (float*)(ws + 524288 + 32514048);
  float* z3  = (float*)(ws + 524288 + 49291264);
  float* e   = (float*)(ws + 524288 + 66068480);
  float* h2  = (float*)(ws + 524288);
  float* h1  = (float*)(ws + 134742016);

  hipMemsetAsync(acc, 0, 64, stream);
  k_prep  <<<308,   256, 0, stream>>>(ew2, ew3, dw1, dw2, dw3, cb, wc2, wc3, wt1, wt2, wt3, c2);
  k_conv1 <<<31752, 256, 0, stream>>>(x, ew1, eb1, z1);
  k_conv2 <<<512,   256, 0, stream>>>(z1, wc2, eb2, z2);
  k_conv3 <<<512,   256, 0, stream>>>(z2, wc3, eb3, z3);
  k_vq    <<<256,   256, 0, stream>>>(z3, cb, c2, e, acc);
  k_convT1<<<2048,  256, 0, stream>>>(e, wt1, db1, h1);
  k_convT2<<<4096,  256, 0, stream>>>(h1, wt2, db2, h2);
  k_convT3<<<3907,  256, 0, stream>>>(h2, wt3, db3, x, out + 3, acc);
  k_fin   <<<1,     64,  0, stream>>>(acc, out);
}

// Round 2
// 577.357 us; speedup vs baseline: 2.1040x; 2.1040x over previous
//
#include <hip/hip_runtime.h>

#define DEV __device__ __forceinline__

// ---------------- geometry ----------------
// x    [64,3,125,125]
// z1p  [64,32,63,64]   conv1 3x3 s2 p1 + relu (row-padded to 64, col63 = 0)
// z2   [64,64,32,32]   conv2 3x3 s2 p1 + relu
// z3   [64,64,32,32]   conv3 1x1
// e    [64,64,32,32]   quantized
// h1   [64,64,64,64]   convT1 3x3 s2 p1 op1 + relu
// h2   [64,32,128,128] convT2 3x3 s2 p1 op1 + relu
// xr   [64,3,125,125]  convT3 2x2 s1 p2

// ---------------- prep: weight transposes + codebook norms ----------------
// wc2p [cog8][ci32][tap9][8]   from enc_w2 [co64][ci32][3][3]
// wc3p [cog8][ci64][8]         from enc_w3 [co64][ci64]
// wt1p [cog8][ci64][tap9][8]   from dec_w1 [ci64][co64][3][3]
// wt2p [cog4][ci64][tap9][8]   from dec_w2 [ci64][co32][3][3]
// wt3  [ci32][kh2][kw2][4]     from dec_w3 [ci32][co3][2][2] (padded co->4)
// c2   [512]                   ||codebook_k||^2
__global__ __launch_bounds__(256) void k_prep(
    const float* __restrict__ ew2, const float* __restrict__ ew3,
    const float* __restrict__ dw1, const float* __restrict__ dw2,
    const float* __restrict__ dw3, const float* __restrict__ cb,
    float* __restrict__ wc2p, float* __restrict__ wc3p,
    float* __restrict__ wt1p, float* __restrict__ wt2p,
    float* __restrict__ wt3, float* __restrict__ c2) {
  int i = blockIdx.x * 256 + threadIdx.x;
  if (i < 18432) {
    int cl = i & 7; int t = i >> 3; int tap = t % 9; t /= 9; int ci = t & 31; int cog = t >> 5;
    wc2p[i] = ew2[((cog * 8 + cl) * 32 + ci) * 9 + tap];
  } else if (i < 22528) {
    int j = i - 18432; int cl = j & 7; int t = j >> 3; int ci = t & 63; int cog = t >> 6;
    wc3p[j] = ew3[(cog * 8 + cl) * 64 + ci];
  } else if (i < 59392) {
    int j = i - 22528; int cl = j & 7; int t = j >> 3; int tap = t % 9; t /= 9; int ci = t & 63; int cog = t >> 6;
    wt1p[j] = dw1[(ci * 64 + cog * 8 + cl) * 9 + tap];
  } else if (i < 77824) {
    int j = i - 59392; int cl = j & 7; int t = j >> 3; int tap = t % 9; t /= 9; int ci = t & 63; int cog = t >> 6;
    wt2p[j] = dw2[(ci * 32 + cog * 8 + cl) * 9 + tap];
  } else if (i < 78336) {
    int j = i - 77824; int co = j & 3; int t = j >> 2; int kw = t & 1; int kh = (t >> 1) & 1; int ci = t >> 2;
    wt3[j] = (co < 3) ? dw3[((ci * 3 + co) * 2 + kh) * 2 + kw] : 0.f;
  } else if (i < 78848) {
    int k = i - 78336;
    const float4* c4 = (const float4*)(cb + (k << 6));
    float s = 0.f;
    #pragma unroll
    for (int q = 0; q < 16; ++q) { float4 v = c4[q]; s += v.x*v.x + v.y*v.y + v.z*v.z + v.w*v.w; }
    c2[k] = s;
  }
}

// ---------------- conv1: 8co x 4ow per thread, LDS weights ----------------
__global__ __launch_bounds__(256, 4) void k_conv1(
    const float* __restrict__ x, const float* __restrict__ ew1,
    const float* __restrict__ bias, float* __restrict__ z1) {
  __shared__ float w[864];  // [ci3][kh3][kw3][co32]
  int t = threadIdx.x;
  for (int i = t; i < 864; i += 256) { int tap = i >> 5, co = i & 31; w[i] = ew1[co * 27 + tap]; }
  __syncthreads();
  int bid = blockIdx.x;              // 1024 = 64b x 4cog x 4ohT
  int ohT = bid & 3; int cog = (bid >> 2) & 3; int b = bid >> 4;
  int tx = t & 15, ty = t >> 4;
  int oh = ohT * 16 + ty; int ow0 = tx * 4; int co0 = cog * 8;
  bool ohok = oh < 63;
  float acc[8][4];
  #pragma unroll
  for (int c = 0; c < 8; ++c) {
    float bv = bias[co0 + c];
    #pragma unroll
    for (int s = 0; s < 4; ++s) acc[c][s] = bv;
  }
  int ih0 = 2 * oh - 1, iw0 = 8 * tx - 1;
  #pragma unroll
  for (int ci = 0; ci < 3; ++ci) {
    #pragma unroll
    for (int kh = 0; kh < 3; ++kh) {
      int ih = ih0 + kh;
      bool hok = ohok && ((unsigned)ih < 125u);
      const float* rp = x + (b * 3 + ci) * 15625 + ih * 125;
      float v[9];
      #pragma unroll
      for (int j = 0; j < 9; ++j) {
        int iw = iw0 + j;
        v[j] = (hok && ((unsigned)iw < 125u)) ? rp[iw] : 0.f;
      }
      #pragma unroll
      for (int kw = 0; kw < 3; ++kw) {
        int tb = (ci * 9 + kh * 3 + kw) * 32 + co0;
        float4 wa = *(const float4*)&w[tb];
        float4 wb = *(const float4*)&w[tb + 4];
        float w8[8] = {wa.x, wa.y, wa.z, wa.w, wb.x, wb.y, wb.z, wb.w};
        #pragma unroll
        for (int s = 0; s < 4; ++s) {
          float in = v[2 * s + kw];
          #pragma unroll
          for (int c = 0; c < 8; ++c) acc[c][s] = fmaf(in, w8[c], acc[c][s]);
        }
      }
    }
  }
  if (ohok) {
    float* op = z1 + ((b * 32 + co0) * 63 + oh) * 64 + ow0;
    #pragma unroll
    for (int c = 0; c < 8; ++c) {
      float4 r;
      r.x = (ow0 + 0 < 63) ? fmaxf(acc[c][0], 0.f) : 0.f;
      r.y = (ow0 + 1 < 63) ? fmaxf(acc[c][1], 0.f) : 0.f;
      r.z = (ow0 + 2 < 63) ? fmaxf(acc[c][2], 0.f) : 0.f;
      r.w = (ow0 + 3 < 63) ? fmaxf(acc[c][3], 0.f) : 0.f;
      *(float4*)(op + c * 4032) = r;
    }
  }
}

// ---------------- conv2: 8co x 4ow per thread, LDS weights ----------------
__global__ __launch_bounds__(256, 4) void k_conv2(
    const float* __restrict__ in,   // z1p [64,32,63,64]
    const float* __restrict__ wp,   // wc2p [cog8][ci32][9][8]
    const float* __restrict__ bias, float* __restrict__ out) { // z2
  __shared__ float w[2304];
  int t = threadIdx.x;
  int bid = blockIdx.x;              // 512 = 64b x 8cog
  int cog = bid & 7; int b = bid >> 3;
  const float* wsrc = wp + cog * 2304;
  #pragma unroll
  for (int i = 0; i < 9; ++i) w[t + 256 * i] = wsrc[t + 256 * i];
  __syncthreads();
  int tx = t & 7, ty = t >> 3;       // ow0 = tx*4 (32 ow), oh = ty (32)
  int ow0 = tx * 4, oh = ty, co0 = cog * 8;
  float acc[8][4];
  #pragma unroll
  for (int c = 0; c < 8; ++c) {
    float bv = bias[co0 + c];
    #pragma unroll
    for (int s = 0; s < 4; ++s) acc[c][s] = bv;
  }
  int ih0 = 2 * oh - 1;
  for (int ci = 0; ci < 32; ++ci) {
    const float* ip = in + (b * 32 + ci) * 4032;
    #pragma unroll
    for (int kh = 0; kh < 3; ++kh) {
      int ih = ih0 + kh;
      bool hok = (unsigned)ih < 63u;
      const float* rp = ip + (ih << 6);
      float v[9];
      if (hok) {
        v[0] = (tx > 0) ? rp[8 * tx - 1] : 0.f;
        float4 qa = *(const float4*)(rp + 8 * tx);
        float4 qb = *(const float4*)(rp + 8 * tx + 4);   // col63 is 0-padding
        v[1] = qa.x; v[2] = qa.y; v[3] = qa.z; v[4] = qa.w;
        v[5] = qb.x; v[6] = qb.y; v[7] = qb.z; v[8] = qb.w;
      } else {
        #pragma unroll
        for (int j = 0; j < 9; ++j) v[j] = 0.f;
      }
      #pragma unroll
      for (int kw = 0; kw < 3; ++kw) {
        int tb = ci * 72 + (kh * 3 + kw) * 8;
        float4 wa = *(const float4*)&w[tb];
        float4 wb = *(const float4*)&w[tb + 4];
        float w8[8] = {wa.x, wa.y, wa.z, wa.w, wb.x, wb.y, wb.z, wb.w};
        #pragma unroll
        for (int s = 0; s < 4; ++s) {
          float in4 = v[2 * s + kw];
          #pragma unroll
          for (int c = 0; c < 8; ++c) acc[c][s] = fmaf(in4, w8[c], acc[c][s]);
        }
      }
    }
  }
  float* op = out + ((b * 64 + co0) * 32 + oh) * 32 + ow0;
  #pragma unroll
  for (int c = 0; c < 8; ++c) {
    float4 r = make_float4(fmaxf(acc[c][0], 0.f), fmaxf(acc[c][1], 0.f),
                           fmaxf(acc[c][2], 0.f), fmaxf(acc[c][3], 0.f));
    *(float4*)(op + c * 1024) = r;
  }
}

// ---------------- conv3 (1x1): 8co x 4px per thread, LDS weights ----------------
__global__ __launch_bounds__(256, 4) void k_conv3(
    const float* __restrict__ in,   // z2 [64,64,1024]
    const float* __restrict__ wp,   // wc3p [cog8][ci64][8]
    const float* __restrict__ bias, float* __restrict__ out) { // z3
  __shared__ float w[512];
  int t = threadIdx.x;
  int bid = blockIdx.x;              // 512 = 64b x 8cog
  int cog = bid & 7; int b = bid >> 3;
  const float* wsrc = wp + cog * 512;
  w[t] = wsrc[t]; w[t + 256] = wsrc[t + 256];
  __syncthreads();
  int px0 = t << 2, co0 = cog * 8;
  float acc[8][4];
  #pragma unroll
  for (int c = 0; c < 8; ++c) {
    float bv = bias[co0 + c];
    #pragma unroll
    for (int s = 0; s < 4; ++s) acc[c][s] = bv;
  }
  const float* ip = in + (b << 16) + px0;
  for (int ci = 0; ci < 64; ++ci) {
    float4 v = *(const float4*)(ip + (ci << 10));
    float4 wa = *(const float4*)&w[ci * 8];
    float4 wb = *(const float4*)&w[ci * 8 + 4];
    float w8[8] = {wa.x, wa.y, wa.z, wa.w, wb.x, wb.y, wb.z, wb.w};
    #pragma unroll
    for (int c = 0; c < 8; ++c) {
      acc[c][0] = fmaf(v.x, w8[c], acc[c][0]);
      acc[c][1] = fmaf(v.y, w8[c], acc[c][1]);
      acc[c][2] = fmaf(v.z, w8[c], acc[c][2]);
      acc[c][3] = fmaf(v.w, w8[c], acc[c][3]);
    }
  }
  float* op = out + ((b << 6) + co0) * 1024 + px0;
  #pragma unroll
  for (int c = 0; c < 8; ++c)
    *(float4*)(op + (c << 10)) = make_float4(acc[c][0], acc[c][1], acc[c][2], acc[c][3]);
}

// ---------------- VQ partial: 4 K-slices, 128 codebook rows each ----------------
__global__ __launch_bounds__(256, 4) void k_vqp(
    const float* __restrict__ z3, const float* __restrict__ cb,
    const float* __restrict__ c2v, float2* __restrict__ pb) {
  int t = threadIdx.x;
  int pxb = blockIdx.x & 255;
  int sl  = blockIdx.x >> 8;         // 0..3
  int n = pxb * 256 + t;
  int b = n >> 10, hw = n & 1023;
  const float* zp = z3 + (b << 16) + hw;
  float z[64];
  #pragma unroll
  for (int d = 0; d < 64; ++d) z[d] = zp[d << 10];
  int k0 = sl << 7;
  float best = 3.4e38f; int bi = k0;
  for (int k = k0; k < k0 + 128; ++k) {
    const float4* c4 = (const float4*)(cb + (k << 6));
    float d0 = 0.f, d1 = 0.f, d2 = 0.f, d3 = 0.f;
    #pragma unroll
    for (int i = 0; i < 16; ++i) {
      float4 c = c4[i];
      d0 = fmaf(z[4 * i + 0], c.x, d0);
      d1 = fmaf(z[4 * i + 1], c.y, d1);
      d2 = fmaf(z[4 * i + 2], c.z, d2);
      d3 = fmaf(z[4 * i + 3], c.w, d3);
    }
    float score = c2v[k] - 2.f * ((d0 + d1) + (d2 + d3));
    if (score < best) { best = score; bi = k; }
  }
  pb[(sl << 16) + n] = make_float2(best, __int_as_float(bi));
}

// ---------------- VQ finalize: merge slices, write e, loss ----------------
__global__ __launch_bounds__(256) void k_vqf(
    const float* __restrict__ z3, const float* __restrict__ cb,
    const float2* __restrict__ pb, float* __restrict__ e,
    float* __restrict__ acc) {
  int n = blockIdx.x * 256 + threadIdx.x;  // 65536
  float best = 3.4e38f; int bi = 0;
  #pragma unroll
  for (int s = 0; s < 4; ++s) {           // ascending slice + strict < == first global argmin
    float2 c = pb[(s << 16) + n];
    if (c.x < best) { best = c.x; bi = __float_as_int(c.y); }
  }
  int b = n >> 10, hw = n & 1023;
  const float* zp = z3 + (b << 16) + hw;
  float* ep = e + (b << 16) + hw;
  const float4* cq = (const float4*)(cb + (bi << 6));
  float lsum = 0.f;
  #pragma unroll
  for (int i = 0; i < 16; ++i) {
    float4 c = cq[i];
    float zv, df;
    zv = zp[(4*i+0) << 10]; ep[(4*i+0) << 10] = c.x; df = c.x - zv; lsum = fmaf(df, df, lsum);
    zv = zp[(4*i+1) << 10]; ep[(4*i+1) << 10] = c.y; df = c.y - zv; lsum = fmaf(df, df, lsum);
    zv = zp[(4*i+2) << 10]; ep[(4*i+2) << 10] = c.z; df = c.z - zv; lsum = fmaf(df, df, lsum);
    zv = zp[(4*i+3) << 10]; ep[(4*i+3) << 10] = c.w; df = c.w - zv; lsum = fmaf(df, df, lsum);
  }
  __shared__ float red[256];
  red[threadIdx.x] = lsum; __syncthreads();
  #pragma unroll
  for (int s = 128; s > 0; s >>= 1) {
    if (threadIdx.x < s) red[threadIdx.x] += red[threadIdx.x + s];
    __syncthreads();
  }
  if (threadIdx.x == 0) atomicAdd(acc + 0, red[0]);
}

// ---------------- convT1: 8co x 8ow per thread, LDS weights ----------------
__global__ __launch_bounds__(256, 3) void k_convT1(
    const float* __restrict__ in,   // e [64,64,32,32]
    const float* __restrict__ wp,   // wt1p [cog8][ci64][9][8]
    const float* __restrict__ bias, float* __restrict__ out) { // h1
  __shared__ float w[4608];
  int t = threadIdx.x;
  int bid = blockIdx.x;              // 1024 = 64b x 8cog x 2ohT
  int ohT = bid & 1; int cog = (bid >> 1) & 7; int b = bid >> 4;
  const float* wsrc = wp + cog * 4608;
  #pragma unroll
  for (int i = 0; i < 18; ++i) w[t + 256 * i] = wsrc[t + 256 * i];
  __syncthreads();
  int tx = t & 7, ty = t >> 3;
  int oh = ohT * 32 + ((ty & 15) << 1) + (ty >> 4);  // waves: uniform oh parity
  int ow0 = tx * 8, x0 = tx * 4, y = oh >> 1, co0 = cog * 8;
  float acc[8][8];
  #pragma unroll
  for (int c = 0; c < 8; ++c) {
    float bv = bias[co0 + c];
    #pragma unroll
    for (int s = 0; s < 8; ++s) acc[c][s] = bv;
  }
  const float* inb = in + (b << 16) + x0;

  auto row = [&](const float* rp, bool hv, int wb) {
    float v[5];
    if (hv) {
      float4 q = *(const float4*)rp;
      v[0] = q.x; v[1] = q.y; v[2] = q.z; v[3] = q.w;
      v[4] = (x0 + 4 < 32) ? rp[4] : 0.f;
    } else { v[0] = v[1] = v[2] = v[3] = v[4] = 0.f; }
    #pragma unroll
    for (int kw = 0; kw < 3; ++kw) {
      float4 wa = *(const float4*)&w[wb + kw * 8];
      float4 wbv = *(const float4*)&w[wb + kw * 8 + 4];
      float w8[8] = {wa.x, wa.y, wa.z, wa.w, wbv.x, wbv.y, wbv.z, wbv.w};
      #pragma unroll
      for (int j = 0; j < 4; ++j) {
        int s = (kw == 1) ? 2 * j : 2 * j + 1;
        float vv = (kw == 0) ? v[j + 1] : v[j];
        #pragma unroll
        for (int c = 0; c < 8; ++c) acc[c][s] = fmaf(vv, w8[c], acc[c][s]);
      }
    }
  };

  if ((oh & 1) == 0) {
    for (int ci = 0; ci < 64; ++ci)
      row(inb + (ci << 10) + (y << 5), true, ci * 72 + 24);            // kh=1, row y
  } else {
    bool hv = (y + 1) < 32;
    for (int ci = 0; ci < 64; ++ci) {
      row(inb + (ci << 10) + ((y + 1) << 5), hv, ci * 72);             // kh=0, row y+1
      row(inb + (ci << 10) + (y << 5), true, ci * 72 + 48);            // kh=2, row y
    }
  }
  float* op = out + (((b << 6) + co0) << 12) + (oh << 6) + ow0;
  #pragma unroll
  for (int c = 0; c < 8; ++c) {
    float4 r0 = make_float4(fmaxf(acc[c][0], 0.f), fmaxf(acc[c][1], 0.f),
                            fmaxf(acc[c][2], 0.f), fmaxf(acc[c][3], 0.f));
    float4 r1 = make_float4(fmaxf(acc[c][4], 0.f), fmaxf(acc[c][5], 0.f),
                            fmaxf(acc[c][6], 0.f), fmaxf(acc[c][7], 0.f));
    *(float4*)(op + (c << 12)) = r0;
    *(float4*)(op + (c << 12) + 4) = r1;
  }
}

// ---------------- convT2: 8co x 8ow per thread, LDS weights ----------------
__global__ __launch_bounds__(256, 3) void k_convT2(
    const float* __restrict__ in,   // h1 [64,64,64,64]
    const float* __restrict__ wp,   // wt2p [cog4][ci64][9][8]
    const float* __restrict__ bias, float* __restrict__ out) { // h2
  __shared__ float w[4608];
  int t = threadIdx.x;
  int bid = blockIdx.x;              // 2048 = 64b x 4cog x 8ohT
  int ohT = bid & 7; int cog = (bid >> 3) & 3; int b = bid >> 5;
  const float* wsrc = wp + cog * 4608;
  #pragma unroll
  for (int i = 0; i < 18; ++i) w[t + 256 * i] = wsrc[t + 256 * i];
  __syncthreads();
  int tx = t & 15, ty = t >> 4;
  int oh = ohT * 16 + ((ty & 7) << 1) + (ty >> 3);  // waves: uniform oh parity
  int ow0 = tx * 8, x0 = tx * 4, y = oh >> 1, co0 = cog * 8;
  float acc[8][8];
  #pragma unroll
  for (int c = 0; c < 8; ++c) {
    float bv = bias[co0 + c];
    #pragma unroll
    for (int s = 0; s < 8; ++s) acc[c][s] = bv;
  }
  const float* inb = in + (b << 18) + x0;

  auto row = [&](const float* rp, bool hv, int wb) {
    float v[5];
    if (hv) {
      float4 q = *(const float4*)rp;
      v[0] = q.x; v[1] = q.y; v[2] = q.z; v[3] = q.w;
      v[4] = (x0 + 4 < 64) ? rp[4] : 0.f;
    } else { v[0] = v[1] = v[2] = v[3] = v[4] = 0.f; }
    #pragma unroll
    for (int kw = 0; kw < 3; ++kw) {
      float4 wa = *(const float4*)&w[wb + kw * 8];
      float4 wbv = *(const float4*)&w[wb + kw * 8 + 4];
      float w8[8] = {wa.x, wa.y, wa.z, wa.w, wbv.x, wbv.y, wbv.z, wbv.w};
      #pragma unroll
      for (int j = 0; j < 4; ++j) {
        int s = (kw == 1) ? 2 * j : 2 * j + 1;
        float vv = (kw == 0) ? v[j + 1] : v[j];
        #pragma unroll
        for (int c = 0; c < 8; ++c) acc[c][s] = fmaf(vv, w8[c], acc[c][s]);
      }
    }
  };

  if ((oh & 1) == 0) {
    for (int ci = 0; ci < 64; ++ci)
      row(inb + (ci << 12) + (y << 6), true, ci * 72 + 24);            // kh=1, row y
  } else {
    bool hv = (y + 1) < 64;
    for (int ci = 0; ci < 64; ++ci) {
      row(inb + (ci << 12) + ((y + 1) << 6), hv, ci * 72);             // kh=0, row y+1
      row(inb + (ci << 12) + (y << 6), true, ci * 72 + 48);            // kh=2, row y
    }
  }
  float* op = out + (((b << 5) + co0) << 14) + (oh << 7) + ow0;
  #pragma unroll
  for (int c = 0; c < 8; ++c) {
    float4 r0 = make_float4(fmaxf(acc[c][0], 0.f), fmaxf(acc[c][1], 0.f),
                            fmaxf(acc[c][2], 0.f), fmaxf(acc[c][3], 0.f));
    float4 r1 = make_float4(fmaxf(acc[c][4], 0.f), fmaxf(acc[c][5], 0.f),
                            fmaxf(acc[c][6], 0.f), fmaxf(acc[c][7], 0.f));
    *(float4*)(op + (c << 14)) = r0;
    *(float4*)(op + (c << 14) + 4) = r1;
  }
}

// ---------------- convT3 + recon loss: 3co x 4ow per thread ----------------
__global__ __launch_bounds__(256) void k_convT3(
    const float* __restrict__ in,   // h2 [64,32,128,128]
    const float* __restrict__ wt,   // wt3 [ci32][2][2][4]
    const float* __restrict__ bias, const float* __restrict__ x,
    float* __restrict__ xr, float* __restrict__ acc) {
  __shared__ float w[512];
  int t = threadIdx.x;
  w[t] = wt[t]; w[t + 256] = wt[t + 256];
  __syncthreads();
  int idx = blockIdx.x * 256 + t;    // 256000 exact
  int owg = idx & 31; int t2 = idx >> 5;
  int oh = t2 % 125; int b = t2 / 125;
  int ow0 = owg * 4;
  float a0 = bias[0], a1 = bias[1], a2 = bias[2];
  float a[3][4];
  #pragma unroll
  for (int s = 0; s < 4; ++s) { a[0][s] = a0; a[1][s] = a1; a[2][s] = a2; }
  const float* inb = in + (b << 19);
  for (int ci = 0; ci < 32; ++ci) {
    #pragma unroll
    for (int kh = 0; kh < 2; ++kh) {
      const float* rp = inb + (ci << 14) + ((oh + 2 - kh) << 7);
      float v[5];
      v[0] = rp[ow0 + 1];
      float2 p = *(const float2*)(rp + ow0 + 2);
      float2 q = *(const float2*)(rp + ow0 + 4);
      v[1] = p.x; v[2] = p.y; v[3] = q.x; v[4] = q.y;
      #pragma unroll
      for (int kw = 0; kw < 2; ++kw) {
        float4 wv = *(const float4*)&w[(ci * 2 + kh) * 8 + kw * 4];
        #pragma unroll
        for (int s = 0; s < 4; ++s) {
          float inv = v[s + 1 - kw];
          a[0][s] = fmaf(inv, wv.x, a[0][s]);
          a[1][s] = fmaf(inv, wv.y, a[1][s]);
          a[2][s] = fmaf(inv, wv.z, a[2][s]);
        }
      }
    }
  }
  int o = b * 46875 + oh * 125 + ow0;
  float lsum = 0.f;
  #pragma unroll
  for (int s = 0; s < 4; ++s) {
    if (ow0 + s < 125) {
      #pragma unroll
      for (int c = 0; c < 3; ++c) {
        float val = a[c][s];
        xr[o + s + c * 15625] = val;
        float d = val - x[o + s + c * 15625];
        lsum = fmaf(d, d, lsum);
      }
    }
  }
  __shared__ float red[256];
  red[t] = lsum; __syncthreads();
  #pragma unroll
  for (int s = 128; s > 0; s >>= 1) {
    if (t < s) red[t] += red[t + s];
    __syncthreads();
  }
  if (t == 0) atomicAdd(acc + 1, red[0]);
}

// ---------------- finalize ----------------
__global__ void k_fin(const float* __restrict__ acc, float* __restrict__ out) {
  if (threadIdx.x == 0 && blockIdx.x == 0) {
    float eq  = 1.25f * acc[0] / 4194304.0f;
    float rec = acc[1];
    out[0] = eq + rec;
    out[1] = eq;
    out[2] = rec;
  }
}

extern "C" void kernel_launch(void* const* d_in, const int* in_sizes, int n_in,
                              void* d_out, int out_size, void* d_ws, size_t ws_size,
                              hipStream_t stream) {
  (void)in_sizes; (void)n_in; (void)out_size; (void)ws_size;
  const float* x   = (const float*)d_in[0];
  const float* ew1 = (const float*)d_in[1];
  const float* eb1 = (const float*)d_in[2];
  const float* ew2 = (const float*)d_in[3];
  const float* eb2 = (const float*)d_in[4];
  const float* ew3 = (const float*)d_in[5];
  const float* eb3 = (const float*)d_in[6];
  const float* cb  = (const float*)d_in[7];
  const float* dw1 = (const float*)d_in[8];
  const float* db1 = (const float*)d_in[9];
  const float* dw2 = (const float*)d_in[10];
  const float* db2 = (const float*)d_in[11];
  const float* dw3 = (const float*)d_in[12];
  const float* db3 = (const float*)d_in[13];
  float* out = (float*)d_out;
  char*  ws  = (char*)d_ws;

  float*  acc  = (float*)(ws + 0);
  float*  c2   = (float*)(ws + 256);
  float*  wc2p = (float*)(ws + 4096);
  float*  wc3p = (float*)(ws + 77824);
  float*  wt1p = (float*)(ws + 94208);
  float*  wt2p = (float*)(ws + 241664);
  float*  wt3  = (float*)(ws + 315392);
  // Region A (524288..): z1p -> (e, pb) -> h2 reuse. h1 separate.
  // Timeline: z1p dead after conv2; z2 dead after conv3; pb written after z1
  // dead; e written at A base (disjoint from pb); z3 dead after vqf;
  // h2 (convT2 output) overwrites e/pb/z3 when all are dead.
  float*  z1   = (float*)(ws + 524288);                 // 33030144 B
  float*  z2   = (float*)(ws + 33554432);               // 16777216 B
  float*  z3   = (float*)(ws + 50331648);               // 16777216 B
  float*  e    = (float*)(ws + 524288);                 // 16777216 B
  float2* pb   = (float2*)(ws + 17301504);              //  2097152 B
  float*  h2   = (float*)(ws + 524288);                 // 134217728 B
  float*  h1   = (float*)(ws + 134742016);              // 67108864 B -> ends 201850880

  hipMemsetAsync(acc, 0, 64, stream);
  k_prep  <<<308,  256, 0, stream>>>(ew2, ew3, dw1, dw2, dw3, cb, wc2p, wc3p, wt1p, wt2p, wt3, c2);
  k_conv1 <<<1024, 256, 0, stream>>>(x, ew1, eb1, z1);
  k_conv2 <<<512,  256, 0, stream>>>(z1, wc2p, eb2, z2);
  k_conv3 <<<512,  256, 0, stream>>>(z2, wc3p, eb3, z3);
  k_vqp   <<<1024, 256, 0, stream>>>(z3, cb, c2, pb);
  k_vqf   <<<256,  256, 0, stream>>>(z3, cb, pb, e, acc);
  k_convT1<<<1024, 256, 0, stream>>>(e, wt1p, db1, h1);
  k_convT2<<<2048, 256, 0, stream>>>(h1, wt2p, db2, h2);
  k_convT3<<<1000, 256, 0, stream>>>(h2, wt3, db3, x, out + 3, acc);
  k_fin   <<<1,    64,  0, stream>>>(acc, out);
}

// Round 3
// 521.951 us; speedup vs baseline: 2.3273x; 1.1062x over previous
//
#include <hip/hip_runtime.h>

#define DEV __device__ __forceinline__

// ---------------- geometry ----------------
// x    [64,3,125,125]
// z1p  [64,32,63,64]   conv1 3x3 s2 p1 + relu (row-padded to 64, col63 = 0)
// z2   [64,64,32,32]   conv2 3x3 s2 p1 + relu
// z3   [64,64,32,32]   conv3 1x1
// e    [64,64,32,32]   quantized
// h1   [64,64,64,64]   convT1 3x3 s2 p1 op1 + relu
// h2   [64,32,128,128] convT2 3x3 s2 p1 op1 + relu
// xr   [64,3,125,125]  convT3 2x2 s1 p2
//
// All weight tables are read with wave-uniform indices -> compiler emits
// s_load through the scalar cache; FMAs are v_fmac v, s, v. No LDS.

// ---------------- prep: weight transposes + codebook norms ----------------
// wc1p [cog4][ci3][tap9][8]    from enc_w1 [co32][ci3][3][3]
// wc2p [cog8][ci32][tap9][8]   from enc_w2 [co64][ci32][3][3]
// wc3p [cog8][ci64][8]         from enc_w3 [co64][ci64]
// wt1p [cog8][ci64][tap9][8]   from dec_w1 [ci64][co64][3][3]
// wt2p [cog4][ci64][tap9][8]   from dec_w2 [ci64][co32][3][3]
// wt3  [ci32][kh2][kw2][4]     from dec_w3 [ci32][co3][2][2] (padded co->4)
// c2   [512]                   ||codebook_k||^2
__global__ __launch_bounds__(256) void k_prep(
    const float* __restrict__ ew1, const float* __restrict__ ew2,
    const float* __restrict__ ew3, const float* __restrict__ dw1,
    const float* __restrict__ dw2, const float* __restrict__ dw3,
    const float* __restrict__ cb,
    float* __restrict__ wc1p, float* __restrict__ wc2p,
    float* __restrict__ wc3p, float* __restrict__ wt1p,
    float* __restrict__ wt2p, float* __restrict__ wt3,
    float* __restrict__ c2) {
  int i = blockIdx.x * 256 + threadIdx.x;
  if (i < 864) {
    int cl = i & 7; int t = i >> 3; int tap = t % 9; t /= 9; int ci = t % 3; int cog = t / 3;
    wc1p[i] = ew1[((cog * 8 + cl) * 3 + ci) * 9 + tap];
  } else if (i < 19296) {
    int j = i - 864; int cl = j & 7; int t = j >> 3; int tap = t % 9; t /= 9; int ci = t & 31; int cog = t >> 5;
    wc2p[j] = ew2[((cog * 8 + cl) * 32 + ci) * 9 + tap];
  } else if (i < 23392) {
    int j = i - 19296; int cl = j & 7; int t = j >> 3; int ci = t & 63; int cog = t >> 6;
    wc3p[j] = ew3[(cog * 8 + cl) * 64 + ci];
  } else if (i < 60256) {
    int j = i - 23392; int cl = j & 7; int t = j >> 3; int tap = t % 9; t /= 9; int ci = t & 63; int cog = t >> 6;
    wt1p[j] = dw1[(ci * 64 + cog * 8 + cl) * 9 + tap];
  } else if (i < 78688) {
    int j = i - 60256; int cl = j & 7; int t = j >> 3; int tap = t % 9; t /= 9; int ci = t & 63; int cog = t >> 6;
    wt2p[j] = dw2[(ci * 32 + cog * 8 + cl) * 9 + tap];
  } else if (i < 79200) {
    int j = i - 78688; int co = j & 3; int t = j >> 2; int kw = t & 1; int kh = (t >> 1) & 1; int ci = t >> 2;
    wt3[j] = (co < 3) ? dw3[((ci * 3 + co) * 2 + kh) * 2 + kw] : 0.f;
  } else if (i < 79712) {
    int k = i - 79200;
    const float4* c4 = (const float4*)(cb + (k << 6));
    float s = 0.f;
    #pragma unroll
    for (int q = 0; q < 16; ++q) { float4 v = c4[q]; s += v.x*v.x + v.y*v.y + v.z*v.z + v.w*v.w; }
    c2[k] = s;
  }
}

// ---------------- conv1: 8co x 4ow per thread, SGPR weights ----------------
__global__ __launch_bounds__(256, 4) void k_conv1(
    const float* __restrict__ x, const float* __restrict__ wp,  // wc1p
    const float* __restrict__ bias, float* __restrict__ z1) {
  int t = threadIdx.x;
  int bid = blockIdx.x;              // 1024 = 64b x 4cog x 4ohT
  int ohT = bid & 3; int cog = (bid >> 2) & 3; int b = bid >> 4;
  const float* wcg = wp + cog * 216;
  int tx = t & 15, ty = t >> 4;
  int oh = ohT * 16 + ty; int ow0 = tx * 4; int co0 = cog * 8;
  bool ohok = oh < 63;
  float acc[8][4];
  #pragma unroll
  for (int c = 0; c < 8; ++c) {
    float bv = bias[co0 + c];
    #pragma unroll
    for (int s = 0; s < 4; ++s) acc[c][s] = bv;
  }
  int ih0 = 2 * oh - 1, iw0 = 8 * tx - 1;
  #pragma unroll
  for (int ci = 0; ci < 3; ++ci) {
    #pragma unroll
    for (int kh = 0; kh < 3; ++kh) {
      int ih = ih0 + kh;
      bool hok = ohok && ((unsigned)ih < 125u);
      const float* rp = x + (b * 3 + ci) * 15625 + ih * 125;
      float v[9];
      #pragma unroll
      for (int j = 0; j < 9; ++j) {
        int iw = iw0 + j;
        v[j] = (hok && ((unsigned)iw < 125u)) ? rp[iw] : 0.f;
      }
      #pragma unroll
      for (int kw = 0; kw < 3; ++kw) {
        const float* wq = wcg + (ci * 9 + kh * 3 + kw) * 8;
        float4 wa = *(const float4*)wq;
        float4 wb = *(const float4*)(wq + 4);
        float w8[8] = {wa.x, wa.y, wa.z, wa.w, wb.x, wb.y, wb.z, wb.w};
        #pragma unroll
        for (int s = 0; s < 4; ++s) {
          float in = v[2 * s + kw];
          #pragma unroll
          for (int c = 0; c < 8; ++c) acc[c][s] = fmaf(in, w8[c], acc[c][s]);
        }
      }
    }
  }
  if (ohok) {
    float* op = z1 + ((b * 32 + co0) * 63 + oh) * 64 + ow0;
    #pragma unroll
    for (int c = 0; c < 8; ++c) {
      float4 r;
      r.x = (ow0 + 0 < 63) ? fmaxf(acc[c][0], 0.f) : 0.f;
      r.y = (ow0 + 1 < 63) ? fmaxf(acc[c][1], 0.f) : 0.f;
      r.z = (ow0 + 2 < 63) ? fmaxf(acc[c][2], 0.f) : 0.f;
      r.w = (ow0 + 3 < 63) ? fmaxf(acc[c][3], 0.f) : 0.f;
      *(float4*)(op + c * 4032) = r;
    }
  }
}

// ---------------- conv2: 8co x 4ow per thread, SGPR weights ----------------
__global__ __launch_bounds__(256, 4) void k_conv2(
    const float* __restrict__ in,   // z1p [64,32,63,64]
    const float* __restrict__ wp,   // wc2p [cog8][ci32][9][8]
    const float* __restrict__ bias, float* __restrict__ out) { // z2
  int t = threadIdx.x;
  int bid = blockIdx.x;              // 512 = 64b x 8cog
  int cog = bid & 7; int b = bid >> 3;
  const float* wcg = wp + cog * 2304;
  int tx = t & 7, ty = t >> 3;
  int ow0 = tx * 4, oh = ty, co0 = cog * 8;
  float acc[8][4];
  #pragma unroll
  for (int c = 0; c < 8; ++c) {
    float bv = bias[co0 + c];
    #pragma unroll
    for (int s = 0; s < 4; ++s) acc[c][s] = bv;
  }
  int ih0 = 2 * oh - 1;
  for (int ci = 0; ci < 32; ++ci) {
    const float* ip = in + (b * 32 + ci) * 4032;
    const float* wci = wcg + ci * 72;
    #pragma unroll
    for (int kh = 0; kh < 3; ++kh) {
      int ih = ih0 + kh;
      bool hok = (unsigned)ih < 63u;
      const float* rp = ip + (ih << 6);
      // unconditional loads: ih in [-1,63] stays inside ws; masked below
      float vm1 = rp[8 * tx - 1];
      float4 qa = *(const float4*)(rp + 8 * tx);
      float4 qb = *(const float4*)(rp + 8 * tx + 4);   // col63 is 0-padding
      float v[9];
      v[0] = (hok && tx > 0) ? vm1 : 0.f;
      v[1] = hok ? qa.x : 0.f; v[2] = hok ? qa.y : 0.f;
      v[3] = hok ? qa.z : 0.f; v[4] = hok ? qa.w : 0.f;
      v[5] = hok ? qb.x : 0.f; v[6] = hok ? qb.y : 0.f;
      v[7] = hok ? qb.z : 0.f; v[8] = hok ? qb.w : 0.f;
      #pragma unroll
      for (int kw = 0; kw < 3; ++kw) {
        const float* wq = wci + (kh * 3 + kw) * 8;
        float4 wa = *(const float4*)wq;
        float4 wb = *(const float4*)(wq + 4);
        float w8[8] = {wa.x, wa.y, wa.z, wa.w, wb.x, wb.y, wb.z, wb.w};
        #pragma unroll
        for (int s = 0; s < 4; ++s) {
          float in4 = v[2 * s + kw];
          #pragma unroll
          for (int c = 0; c < 8; ++c) acc[c][s] = fmaf(in4, w8[c], acc[c][s]);
        }
      }
    }
  }
  float* op = out + ((b * 64 + co0) * 32 + oh) * 32 + ow0;
  #pragma unroll
  for (int c = 0; c < 8; ++c) {
    float4 r = make_float4(fmaxf(acc[c][0], 0.f), fmaxf(acc[c][1], 0.f),
                           fmaxf(acc[c][2], 0.f), fmaxf(acc[c][3], 0.f));
    *(float4*)(op + c * 1024) = r;
  }
}

// ---------------- conv3 (1x1): 8co x 4px per thread, SGPR weights ----------------
__global__ __launch_bounds__(256, 4) void k_conv3(
    const float* __restrict__ in,   // z2 [64,64,1024]
    const float* __restrict__ wp,   // wc3p [cog8][ci64][8]
    const float* __restrict__ bias, float* __restrict__ out) { // z3
  int t = threadIdx.x;
  int bid = blockIdx.x;              // 512 = 64b x 8cog
  int cog = bid & 7; int b = bid >> 3;
  const float* wcg = wp + cog * 512;
  int px0 = t << 2, co0 = cog * 8;
  float acc[8][4];
  #pragma unroll
  for (int c = 0; c < 8; ++c) {
    float bv = bias[co0 + c];
    #pragma unroll
    for (int s = 0; s < 4; ++s) acc[c][s] = bv;
  }
  const float* ip = in + (b << 16) + px0;
  for (int ci = 0; ci < 64; ++ci) {
    float4 v = *(const float4*)(ip + (ci << 10));
    float4 wa = *(const float4*)(wcg + ci * 8);
    float4 wb = *(const float4*)(wcg + ci * 8 + 4);
    float w8[8] = {wa.x, wa.y, wa.z, wa.w, wb.x, wb.y, wb.z, wb.w};
    #pragma unroll
    for (int c = 0; c < 8; ++c) {
      acc[c][0] = fmaf(v.x, w8[c], acc[c][0]);
      acc[c][1] = fmaf(v.y, w8[c], acc[c][1]);
      acc[c][2] = fmaf(v.z, w8[c], acc[c][2]);
      acc[c][3] = fmaf(v.w, w8[c], acc[c][3]);
    }
  }
  float* op = out + ((b << 6) + co0) * 1024 + px0;
  #pragma unroll
  for (int c = 0; c < 8; ++c)
    *(float4*)(op + (c << 10)) = make_float4(acc[c][0], acc[c][1], acc[c][2], acc[c][3]);
}

// ---------------- VQ partial: 4 K-slices, SGPR codebook ----------------
__global__ __launch_bounds__(256, 4) void k_vqp(
    const float* __restrict__ z3, const float* __restrict__ cb,
    const float* __restrict__ c2v, float2* __restrict__ pb) {
  int t = threadIdx.x;
  int pxb = blockIdx.x & 255;
  int sl  = blockIdx.x >> 8;         // 0..3
  int n = pxb * 256 + t;
  int b = n >> 10, hw = n & 1023;
  const float* zp = z3 + (b << 16) + hw;
  float z[64];
  #pragma unroll
  for (int d = 0; d < 64; ++d) z[d] = zp[d << 10];
  int k0 = sl << 7;
  float best = 3.4e38f; int bi = k0;
  for (int k = k0; k < k0 + 128; ++k) {
    const float4* c4 = (const float4*)(cb + (k << 6));
    float d0 = 0.f, d1 = 0.f, d2 = 0.f, d3 = 0.f;
    #pragma unroll
    for (int i = 0; i < 16; ++i) {
      float4 c = c4[i];
      d0 = fmaf(z[4 * i + 0], c.x, d0);
      d1 = fmaf(z[4 * i + 1], c.y, d1);
      d2 = fmaf(z[4 * i + 2], c.z, d2);
      d3 = fmaf(z[4 * i + 3], c.w, d3);
    }
    float score = c2v[k] - 2.f * ((d0 + d1) + (d2 + d3));
    if (score < best) { best = score; bi = k; }
  }
  pb[(sl << 16) + n] = make_float2(best, __int_as_float(bi));
}

// ---------------- VQ finalize: merge slices, write e, loss ----------------
__global__ __launch_bounds__(256) void k_vqf(
    const float* __restrict__ z3, const float* __restrict__ cb,
    const float2* __restrict__ pb, float* __restrict__ e,
    float* __restrict__ acc) {
  int n = blockIdx.x * 256 + threadIdx.x;  // 65536
  float best = 3.4e38f; int bi = 0;
  #pragma unroll
  for (int s = 0; s < 4; ++s) {           // ascending slice + strict < == first global argmin
    float2 c = pb[(s << 16) + n];
    if (c.x < best) { best = c.x; bi = __float_as_int(c.y); }
  }
  int b = n >> 10, hw = n & 1023;
  const float* zp = z3 + (b << 16) + hw;
  float* ep = e + (b << 16) + hw;
  const float4* cq = (const float4*)(cb + (bi << 6));
  float lsum = 0.f;
  #pragma unroll
  for (int i = 0; i < 16; ++i) {
    float4 c = cq[i];
    float zv, df;
    zv = zp[(4*i+0) << 10]; ep[(4*i+0) << 10] = c.x; df = c.x - zv; lsum = fmaf(df, df, lsum);
    zv = zp[(4*i+1) << 10]; ep[(4*i+1) << 10] = c.y; df = c.y - zv; lsum = fmaf(df, df, lsum);
    zv = zp[(4*i+2) << 10]; ep[(4*i+2) << 10] = c.z; df = c.z - zv; lsum = fmaf(df, df, lsum);
    zv = zp[(4*i+3) << 10]; ep[(4*i+3) << 10] = c.w; df = c.w - zv; lsum = fmaf(df, df, lsum);
  }
  __shared__ float red[256];
  red[threadIdx.x] = lsum; __syncthreads();
  #pragma unroll
  for (int s = 128; s > 0; s >>= 1) {
    if (threadIdx.x < s) red[threadIdx.x] += red[threadIdx.x + s];
    __syncthreads();
  }
  if (threadIdx.x == 0) atomicAdd(acc + 0, red[0]);
}

// ---------------- convT row helper: parity-exact, SGPR weights ----------------
// rp points at input row + x0 (16B aligned). Loads rp[0..4] unconditionally
// (in-bounds via buffer layout), masks with hv (row valid) / edge (x0+4<WIN).
DEV void trowT(const float* __restrict__ rp, bool hv, bool edge,
               const float* __restrict__ wkh, float acc[8][8]) {
  float4 q = *(const float4*)rp;
  float q4 = rp[4];
  float v[5];
  v[0] = hv ? q.x : 0.f; v[1] = hv ? q.y : 0.f;
  v[2] = hv ? q.z : 0.f; v[3] = hv ? q.w : 0.f;
  v[4] = (hv && edge) ? q4 : 0.f;
  #pragma unroll
  for (int kw = 0; kw < 3; ++kw) {
    float4 wa = *(const float4*)(wkh + kw * 8);      // uniform -> s_load
    float4 wb = *(const float4*)(wkh + kw * 8 + 4);
    float w8[8] = {wa.x, wa.y, wa.z, wa.w, wb.x, wb.y, wb.z, wb.w};
    #pragma unroll
    for (int j = 0; j < 4; ++j) {
      int s = (kw == 1) ? 2 * j : 2 * j + 1;
      float vv = (kw == 0) ? v[j + 1] : v[j];
      #pragma unroll
      for (int c = 0; c < 8; ++c) acc[c][s] = fmaf(vv, w8[c], acc[c][s]);
    }
  }
}

// ---------------- convT1: 8co x 8ow per thread ----------------
__global__ __launch_bounds__(256, 3) void k_convT1(
    const float* __restrict__ in,   // e [64,64,32,32]
    const float* __restrict__ wp,   // wt1p [cog8][ci64][9][8]
    const float* __restrict__ bias, float* __restrict__ out) { // h1
  int t = threadIdx.x;
  int bid = blockIdx.x;              // 1024 = 64b x 8cog x 2ohT
  int ohT = bid & 1; int cog = (bid >> 1) & 7; int b = bid >> 4;
  const float* wcg = wp + cog * 4608;
  int tx = t & 7, ty = t >> 3;
  int oh = ohT * 32 + ((ty & 15) << 1) + (ty >> 4);  // wave-uniform parity
  int ow0 = tx * 8, x0 = tx * 4, y = oh >> 1, co0 = cog * 8;
  bool edge = tx < 7;
  float acc[8][8];
  #pragma unroll
  for (int c = 0; c < 8; ++c) {
    float bv = bias[co0 + c];
    #pragma unroll
    for (int s = 0; s < 8; ++s) acc[c][s] = bv;
  }
  const float* inb = in + (b << 16) + x0;
  if ((oh & 1) == 0) {               // kh=1 only, row y
    for (int ci = 0; ci < 64; ++ci)
      trowT(inb + (ci << 10) + (y << 5), true, edge, wcg + ci * 72 + 24, acc);
  } else {                           // kh=0 row y+1 (masked), kh=2 row y
    bool hv = (y + 1) < 32;
    for (int ci = 0; ci < 64; ++ci) {
      trowT(inb + (ci << 10) + ((y + 1) << 5), hv, edge, wcg + ci * 72, acc);
      trowT(inb + (ci << 10) + (y << 5), true, edge, wcg + ci * 72 + 48, acc);
    }
  }
  float* op = out + (((b << 6) + co0) << 12) + (oh << 6) + ow0;
  #pragma unroll
  for (int c = 0; c < 8; ++c) {
    float4 r0 = make_float4(fmaxf(acc[c][0], 0.f), fmaxf(acc[c][1], 0.f),
                            fmaxf(acc[c][2], 0.f), fmaxf(acc[c][3], 0.f));
    float4 r1 = make_float4(fmaxf(acc[c][4], 0.f), fmaxf(acc[c][5], 0.f),
                            fmaxf(acc[c][6], 0.f), fmaxf(acc[c][7], 0.f));
    *(float4*)(op + (c << 12)) = r0;
    *(float4*)(op + (c << 12) + 4) = r1;
  }
}

// ---------------- convT2: 8co x 8ow per thread ----------------
__global__ __launch_bounds__(256, 3) void k_convT2(
    const float* __restrict__ in,   // h1 [64,64,64,64]
    const float* __restrict__ wp,   // wt2p [cog4][ci64][9][8]
    const float* __restrict__ bias, float* __restrict__ out) { // h2
  int t = threadIdx.x;
  int bid = blockIdx.x;              // 2048 = 64b x 4cog x 8ohT
  int ohT = bid & 7; int cog = (bid >> 3) & 3; int b = bid >> 5;
  const float* wcg = wp + cog * 4608;
  int tx = t & 15, ty = t >> 4;
  int oh = ohT * 16 + ((ty & 7) << 1) + (ty >> 3);  // wave-uniform parity
  int ow0 = tx * 8, x0 = tx * 4, y = oh >> 1, co0 = cog * 8;
  bool edge = tx < 15;
  float acc[8][8];
  #pragma unroll
  for (int c = 0; c < 8; ++c) {
    float bv = bias[co0 + c];
    #pragma unroll
    for (int s = 0; s < 8; ++s) acc[c][s] = bv;
  }
  const float* inb = in + (b << 18) + x0;
  if ((oh & 1) == 0) {
    for (int ci = 0; ci < 64; ++ci)
      trowT(inb + (ci << 12) + (y << 6), true, edge, wcg + ci * 72 + 24, acc);
  } else {
    bool hv = (y + 1) < 64;
    for (int ci = 0; ci < 64; ++ci) {
      trowT(inb + (ci << 12) + ((y + 1) << 6), hv, edge, wcg + ci * 72, acc);
      trowT(inb + (ci << 12) + (y << 6), true, edge, wcg + ci * 72 + 48, acc);
    }
  }
  float* op = out + (((b << 5) + co0) << 14) + (oh << 7) + ow0;
  #pragma unroll
  for (int c = 0; c < 8; ++c) {
    float4 r0 = make_float4(fmaxf(acc[c][0], 0.f), fmaxf(acc[c][1], 0.f),
                            fmaxf(acc[c][2], 0.f), fmaxf(acc[c][3], 0.f));
    float4 r1 = make_float4(fmaxf(acc[c][4], 0.f), fmaxf(acc[c][5], 0.f),
                            fmaxf(acc[c][6], 0.f), fmaxf(acc[c][7], 0.f));
    *(float4*)(op + (c << 14)) = r0;
    *(float4*)(op + (c << 14) + 4) = r1;
  }
}

// ---------------- convT3 + recon loss: 3co x 8ow per thread ----------------
__global__ __launch_bounds__(256, 4) void k_convT3(
    const float* __restrict__ in,   // h2 [64,32,128,128]
    const float* __restrict__ wt,   // wt3 [ci32][2][2][4]
    const float* __restrict__ bias, const float* __restrict__ x,
    float* __restrict__ xr, float* __restrict__ acc) {
  int t = threadIdx.x;
  int idx = blockIdx.x * 256 + t;    // 128000 exact
  int owg = idx & 15; int t2 = idx >> 4;
  int oh = t2 % 125; int b = t2 / 125;
  int ow0 = owg * 8;
  float b0 = bias[0], b1 = bias[1], b2 = bias[2];
  float a[3][8];
  #pragma unroll
  for (int s = 0; s < 8; ++s) { a[0][s] = b0; a[1][s] = b1; a[2][s] = b2; }
  const float* inb = in + (b << 19) + ow0;
  for (int ci = 0; ci < 32; ++ci) {
    #pragma unroll
    for (int kh = 0; kh < 2; ++kh) {
      const float* rp = inb + (ci << 14) + ((oh + 2 - kh) << 7);
      float4 qa = *(const float4*)rp;
      float4 qb = *(const float4*)(rp + 4);
      float2 qc = *(const float2*)(rp + 8);
      float v[10] = {qa.x, qa.y, qa.z, qa.w, qb.x, qb.y, qb.z, qb.w, qc.x, qc.y};
      #pragma unroll
      for (int kw = 0; kw < 2; ++kw) {
        float4 wv = *(const float4*)(wt + ((ci * 2 + kh) * 2 + kw) * 4);  // uniform
        #pragma unroll
        for (int s = 0; s < 8; ++s) {
          float inv = v[s + 2 - kw];
          a[0][s] = fmaf(inv, wv.x, a[0][s]);
          a[1][s] = fmaf(inv, wv.y, a[1][s]);
          a[2][s] = fmaf(inv, wv.z, a[2][s]);
        }
      }
    }
  }
  int o = b * 46875 + oh * 125 + ow0;
  float lsum = 0.f;
  #pragma unroll
  for (int s = 0; s < 8; ++s) {
    if (ow0 + s < 125) {
      #pragma unroll
      for (int c = 0; c < 3; ++c) {
        float val = a[c][s];
        xr[o + s + c * 15625] = val;
        float d = val - x[o + s + c * 15625];
        lsum = fmaf(d, d, lsum);
      }
    }
  }
  __shared__ float red[256];
  red[t] = lsum; __syncthreads();
  #pragma unroll
  for (int s = 128; s > 0; s >>= 1) {
    if (t < s) red[t] += red[t + s];
    __syncthreads();
  }
  if (t == 0) atomicAdd(acc + 1, red[0]);
}

// ---------------- finalize ----------------
__global__ void k_fin(const float* __restrict__ acc, float* __restrict__ out) {
  if (threadIdx.x == 0 && blockIdx.x == 0) {
    float eq  = 1.25f * acc[0] / 4194304.0f;
    float rec = acc[1];
    out[0] = eq + rec;
    out[1] = eq;
    out[2] = rec;
  }
}

extern "C" void kernel_launch(void* const* d_in, const int* in_sizes, int n_in,
                              void* d_out, int out_size, void* d_ws, size_t ws_size,
                              hipStream_t stream) {
  (void)in_sizes; (void)n_in; (void)out_size; (void)ws_size;
  const float* x   = (const float*)d_in[0];
  const float* ew1 = (const float*)d_in[1];
  const float* eb1 = (const float*)d_in[2];
  const float* ew2 = (const float*)d_in[3];
  const float* eb2 = (const float*)d_in[4];
  const float* ew3 = (const float*)d_in[5];
  const float* eb3 = (const float*)d_in[6];
  const float* cb  = (const float*)d_in[7];
  const float* dw1 = (const float*)d_in[8];
  const float* db1 = (const float*)d_in[9];
  const float* dw2 = (const float*)d_in[10];
  const float* db2 = (const float*)d_in[11];
  const float* dw3 = (const float*)d_in[12];
  const float* db3 = (const float*)d_in[13];
  float* out = (float*)d_out;
  char*  ws  = (char*)d_ws;

  float*  acc  = (float*)(ws + 0);
  float*  c2   = (float*)(ws + 256);
  float*  wc1p = (float*)(ws + 4096);
  float*  wc2p = (float*)(ws + 8192);
  float*  wc3p = (float*)(ws + 81920);
  float*  wt1p = (float*)(ws + 98304);
  float*  wt2p = (float*)(ws + 245760);
  float*  wt3  = (float*)(ws + 319488);
  // Region reuse (same 201.85 MB footprint as R2):
  // z1 dead after conv2; z2 dead after conv3; z3,pb dead after vqf;
  // e (at base, over dead z1) dead after convT1; h2 overwrites e/z*/pb.
  float*  z1   = (float*)(ws + 524288);                 // 33030144 B
  float*  z2   = (float*)(ws + 33554432);               // 16777216 B
  float*  z3   = (float*)(ws + 50331648);               // 16777216 B
  float2* pb   = (float2*)(ws + 67108864);              //  2097152 B
  float*  e    = (float*)(ws + 524288);                 // 16777216 B
  float*  h2   = (float*)(ws + 524288);                 // 134217728 B
  float*  h1   = (float*)(ws + 134742016);              // 67108864 B -> 201850880

  hipMemsetAsync(acc, 0, 64, stream);
  k_prep  <<<312,  256, 0, stream>>>(ew1, ew2, ew3, dw1, dw2, dw3, cb,
                                     wc1p, wc2p, wc3p, wt1p, wt2p, wt3, c2);
  k_conv1 <<<1024, 256, 0, stream>>>(x, wc1p, eb1, z1);
  k_conv2 <<<512,  256, 0, stream>>>(z1, wc2p, eb2, z2);
  k_conv3 <<<512,  256, 0, stream>>>(z2, wc3p, eb3, z3);
  k_vqp   <<<1024, 256, 0, stream>>>(z3, cb, c2, pb);
  k_vqf   <<<256,  256, 0, stream>>>(z3, cb, pb, e, acc);
  k_convT1<<<1024, 256, 0, stream>>>(e, wt1p, db1, h1);
  k_convT2<<<2048, 256, 0, stream>>>(h1, wt2p, db2, h2);
  k_convT3<<<500,  256, 0, stream>>>(h2, wt3, db3, x, out + 3, acc);
  k_fin   <<<1,    64,  0, stream>>>(acc, out);
}

// Round 4
// 441.287 us; speedup vs baseline: 2.7527x; 1.1828x over previous
//
#include <hip/hip_runtime.h>

#define DEV __device__ __forceinline__
typedef unsigned short u16;
typedef __bf16 bf16x8 __attribute__((ext_vector_type(8)));
typedef float f32x4 __attribute__((ext_vector_type(4)));

DEV u16 f2bf(float f) {                      // RNE f32 -> bf16
  unsigned u = __float_as_uint(f);
  u += 0x7FFF + ((u >> 16) & 1);
  return (u16)(u >> 16);
}

// ---------------- geometry ----------------
// x    [64,3,125,125] fp32
// z1t  [64,63,64,32]  bf16 (w padded to 64, col63=0)   conv1 out
// z2   [64,64,32,32]  fp32                             conv2 out (MFMA)
// z3   [64,64,32,32]  fp32                             conv3 out
// e_t  [64,32,32,64]  bf16                             VQ out (pixel-major, ci contig)
// h1t  [64,64,64,64]  bf16                             convT1 out (MFMA)
// h2   [64,32,128,128] fp32                            convT2 out (MFMA)
// xr   [64,3,125,125] fp32
//
// MFMA 16x16x32 bf16 layouts (per guide, HW-verified):
//   A[m=lane&15][k=(lane>>4)*8+j]   B[k=(lane>>4)*8+j][n=lane&15]
//   D col=lane&15 (=n), row=(lane>>4)*4+reg (=m)

// ---------------- prep ----------------
// wc1p [cog4][ci3][tap9][8] fp32        conv1 weights
// wc3p [cog8][ci64][8] fp32             conv3 weights
// wt3  [ci32][kh2][kw2][4] fp32         convT3 weights (co padded to 4)
// c2   [512] fp32                       ||codebook||^2
// w2f  [tap9][nf4][lane64][8] bf16      conv2  B-frags (K=32=ci)
// wt1f [tap9][s2][nf4][lane64][8] bf16  convT1 B-frags (K=64=ci, 2 kslices)
// wt2f [tap9][s2][nf2][lane64][8] bf16  convT2 B-frags
__global__ __launch_bounds__(256) void k_prep(
    const float* __restrict__ ew1, const float* __restrict__ ew2,
    const float* __restrict__ ew3, const float* __restrict__ dw1,
    const float* __restrict__ dw2, const float* __restrict__ dw3,
    const float* __restrict__ cb,
    float* __restrict__ wc1p, float* __restrict__ wc3p,
    float* __restrict__ wt3, float* __restrict__ c2,
    u16* __restrict__ w2f, u16* __restrict__ wt1f, u16* __restrict__ wt2f) {
  int i = blockIdx.x * 256 + threadIdx.x;
  if (i < 864) {
    int cl = i & 7; int t = i >> 3; int tap = t % 9; t /= 9; int ci = t % 3; int cog = t / 3;
    wc1p[i] = ew1[((cog * 8 + cl) * 3 + ci) * 9 + tap];
  } else if (i < 4960) {
    int j = i - 864; int cl = j & 7; int t = j >> 3; int ci = t & 63; int cog = t >> 6;
    wc3p[j] = ew3[(cog * 8 + cl) * 64 + ci];
  } else if (i < 5472) {
    int j = i - 4960; int co = j & 3; int t = j >> 2; int kw = t & 1; int kh = (t >> 1) & 1; int ci = t >> 2;
    wt3[j] = (co < 3) ? dw3[((ci * 3 + co) * 2 + kh) * 2 + kw] : 0.f;
  } else if (i < 5984) {
    int k = i - 5472;
    const float4* c4 = (const float4*)(cb + (k << 6));
    float s = 0.f;
    #pragma unroll
    for (int q = 0; q < 16; ++q) { float4 v = c4[q]; s += v.x*v.x + v.y*v.y + v.z*v.z + v.w*v.w; }
    c2[k] = s;
  } else if (i < 24416) {
    int j = i - 5984;                       // [kt][nf][lane][8]
    int jj = j & 7; int lane = (j >> 3) & 63; int nf = (j >> 9) & 3; int kt = j >> 11;
    int kh = kt / 3, kw = kt % 3;
    int ci = ((lane >> 4) << 3) + jj; int co = (nf << 4) + (lane & 15);
    w2f[j] = f2bf(ew2[((co * 32 + ci) * 3 + kh) * 3 + kw]);
  } else if (i < 61280) {
    int j = i - 24416;                      // [kt][s][nf][lane][8]
    int jj = j & 7; int lane = (j >> 3) & 63; int nf = (j >> 9) & 3; int s = (j >> 11) & 1; int kt = j >> 12;
    int kh = kt / 3, kw = kt % 3;
    int ci = (s << 5) + ((lane >> 4) << 3) + jj; int co = (nf << 4) + (lane & 15);
    wt1f[j] = f2bf(dw1[((ci * 64 + co) * 3 + kh) * 3 + kw]);
  } else if (i < 79712) {
    int j = i - 61280;                      // [kt][s][nf][lane][8]
    int jj = j & 7; int lane = (j >> 3) & 63; int nf = (j >> 9) & 1; int s = (j >> 10) & 1; int kt = j >> 11;
    int kh = kt / 3, kw = kt % 3;
    int ci = (s << 5) + ((lane >> 4) << 3) + jj; int co = (nf << 4) + (lane & 15);
    wt2f[j] = f2bf(dw2[((ci * 32 + co) * 3 + kh) * 3 + kw]);
  }
}

// ---------------- conv1: fp32 VALU, 8co x 4ow/thread, out z1t bf16 ----------------
__global__ __launch_bounds__(256, 4) void k_conv1(
    const float* __restrict__ x, const float* __restrict__ wp,
    const float* __restrict__ bias, u16* __restrict__ z1t) {
  int t = threadIdx.x;
  int bid = blockIdx.x;              // 1024 = 64b x 4cog x 4ohT
  int ohT = bid & 3; int cog = (bid >> 2) & 3; int b = bid >> 4;
  const float* wcg = wp + cog * 216;
  int tx = t & 15, ty = t >> 4;
  int oh = ohT * 16 + ty; int ow0 = tx * 4; int co0 = cog * 8;
  bool ohok = oh < 63;
  float acc[8][4];
  #pragma unroll
  for (int c = 0; c < 8; ++c) {
    float bv = bias[co0 + c];
    #pragma unroll
    for (int s = 0; s < 4; ++s) acc[c][s] = bv;
  }
  int ih0 = 2 * oh - 1, iw0 = 8 * tx - 1;
  #pragma unroll
  for (int ci = 0; ci < 3; ++ci) {
    #pragma unroll
    for (int kh = 0; kh < 3; ++kh) {
      int ih = ih0 + kh;
      bool hok = ohok && ((unsigned)ih < 125u);
      const float* rp = x + (b * 3 + ci) * 15625 + ih * 125;
      float v[9];
      #pragma unroll
      for (int j = 0; j < 9; ++j) {
        int iw = iw0 + j;
        v[j] = (hok && ((unsigned)iw < 125u)) ? rp[iw] : 0.f;
      }
      #pragma unroll
      for (int kw = 0; kw < 3; ++kw) {
        const float* wq = wcg + (ci * 9 + kh * 3 + kw) * 8;
        float4 wa = *(const float4*)wq;
        float4 wb = *(const float4*)(wq + 4);
        float w8[8] = {wa.x, wa.y, wa.z, wa.w, wb.x, wb.y, wb.z, wb.w};
        #pragma unroll
        for (int s = 0; s < 4; ++s) {
          float in = v[2 * s + kw];
          #pragma unroll
          for (int c = 0; c < 8; ++c) acc[c][s] = fmaf(in, w8[c], acc[c][s]);
        }
      }
    }
  }
  if (ohok) {
    u16* op = z1t + ((b * 63 + oh) * 64 + ow0) * 32 + co0;
    #pragma unroll
    for (int s = 0; s < 4; ++s) {
      bool wok = (ow0 + s) < 63;
      unsigned p0 = 0, p1 = 0, p2 = 0, p3 = 0;
      if (wok) {
        p0 = f2bf(fmaxf(acc[0][s], 0.f)) | ((unsigned)f2bf(fmaxf(acc[1][s], 0.f)) << 16);
        p1 = f2bf(fmaxf(acc[2][s], 0.f)) | ((unsigned)f2bf(fmaxf(acc[3][s], 0.f)) << 16);
        p2 = f2bf(fmaxf(acc[4][s], 0.f)) | ((unsigned)f2bf(fmaxf(acc[5][s], 0.f)) << 16);
        p3 = f2bf(fmaxf(acc[6][s], 0.f)) | ((unsigned)f2bf(fmaxf(acc[7][s], 0.f)) << 16);
      }
      *(uint4*)(op + s * 32) = make_uint4(p0, p1, p2, p3);
    }
  }
}

// ---------------- conv2: MFMA, block=(b,oh), waves=(xt2, ch2) ----------------
__global__ __launch_bounds__(256) void k_conv2(
    const u16* __restrict__ z1t, const u16* __restrict__ wf,
    const float* __restrict__ bias, float* __restrict__ z2) {
  int t = threadIdx.x;
  int lane = t & 63, wv = t >> 6;
  int n = lane & 15, q = lane >> 4;
  int oh = blockIdx.x & 31, b = blockIdx.x >> 5;   // grid 2048
  int xt = wv & 1, ch = wv >> 1;
  int xA = xt * 16 + n;
  f32x4 acc[2] = {{0,0,0,0},{0,0,0,0}};
  #pragma unroll
  for (int kh = 0; kh < 3; ++kh) {
    int ih = 2 * oh - 1 + kh;
    bool yok = (unsigned)ih < 63u;
    #pragma unroll
    for (int kw = 0; kw < 3; ++kw) {
      int iw = 2 * xA - 1 + kw;
      bool ok = yok && (iw >= 0);                  // iw==63 reads zero-pad col
      bf16x8 a = {};
      if (ok) a = *(const bf16x8*)(z1t + ((b * 63 + ih) * 64 + iw) * 32 + q * 8);
      int kt = kh * 3 + kw;
      const u16* wb = wf + ((kt << 2) + (ch << 1)) * 512 + lane * 8;
      bf16x8 b0 = *(const bf16x8*)wb;
      bf16x8 b1 = *(const bf16x8*)(wb + 512);
      acc[0] = __builtin_amdgcn_mfma_f32_16x16x32_bf16(a, b0, acc[0], 0, 0, 0);
      acc[1] = __builtin_amdgcn_mfma_f32_16x16x32_bf16(a, b1, acc[1], 0, 0, 0);
    }
  }
  #pragma unroll
  for (int j = 0; j < 2; ++j) {
    int co = ((ch << 1) + j) * 16 + n;
    float bv = bias[co];
    #pragma unroll
    for (int r = 0; r < 4; ++r) {
      int ow = xt * 16 + q * 4 + r;
      z2[((b * 64 + co) * 32 + oh) * 32 + ow] = fmaxf(acc[j][r] + bv, 0.f);
    }
  }
}

// ---------------- conv3 (1x1): fp32, 8co x 4px/thread ----------------
__global__ __launch_bounds__(256, 4) void k_conv3(
    const float* __restrict__ in, const float* __restrict__ wp,
    const float* __restrict__ bias, float* __restrict__ out) {
  int t = threadIdx.x;
  int bid = blockIdx.x;              // 512 = 64b x 8cog
  int cog = bid & 7; int b = bid >> 3;
  const float* wcg = wp + cog * 512;
  int px0 = t << 2, co0 = cog * 8;
  float acc[8][4];
  #pragma unroll
  for (int c = 0; c < 8; ++c) {
    float bv = bias[co0 + c];
    #pragma unroll
    for (int s = 0; s < 4; ++s) acc[c][s] = bv;
  }
  const float* ip = in + (b << 16) + px0;
  for (int ci = 0; ci < 64; ++ci) {
    float4 v = *(const float4*)(ip + (ci << 10));
    float4 wa = *(const float4*)(wcg + ci * 8);
    float4 wb = *(const float4*)(wcg + ci * 8 + 4);
    float w8[8] = {wa.x, wa.y, wa.z, wa.w, wb.x, wb.y, wb.z, wb.w};
    #pragma unroll
    for (int c = 0; c < 8; ++c) {
      acc[c][0] = fmaf(v.x, w8[c], acc[c][0]);
      acc[c][1] = fmaf(v.y, w8[c], acc[c][1]);
      acc[c][2] = fmaf(v.z, w8[c], acc[c][2]);
      acc[c][3] = fmaf(v.w, w8[c], acc[c][3]);
    }
  }
  float* op = out + ((b << 6) + co0) * 1024 + px0;
  #pragma unroll
  for (int c = 0; c < 8; ++c)
    *(float4*)(op + (c << 10)) = make_float4(acc[c][0], acc[c][1], acc[c][2], acc[c][3]);
}

// ---------------- VQ partial: 4 K-slices (fp32 exact) ----------------
__global__ __launch_bounds__(256, 4) void k_vqp(
    const float* __restrict__ z3, const float* __restrict__ cb,
    const float* __restrict__ c2v, float2* __restrict__ pb) {
  int t = threadIdx.x;
  int pxb = blockIdx.x & 255;
  int sl  = blockIdx.x >> 8;
  int n = pxb * 256 + t;
  int b = n >> 10, hw = n & 1023;
  const float* zp = z3 + (b << 16) + hw;
  float z[64];
  #pragma unroll
  for (int d = 0; d < 64; ++d) z[d] = zp[d << 10];
  int k0 = sl << 7;
  float best = 3.4e38f; int bi = k0;
  for (int k = k0; k < k0 + 128; ++k) {
    const float4* c4 = (const float4*)(cb + (k << 6));
    float d0 = 0.f, d1 = 0.f, d2 = 0.f, d3 = 0.f;
    #pragma unroll
    for (int i = 0; i < 16; ++i) {
      float4 c = c4[i];
      d0 = fmaf(z[4 * i + 0], c.x, d0);
      d1 = fmaf(z[4 * i + 1], c.y, d1);
      d2 = fmaf(z[4 * i + 2], c.z, d2);
      d3 = fmaf(z[4 * i + 3], c.w, d3);
    }
    float score = c2v[k] - 2.f * ((d0 + d1) + (d2 + d3));
    if (score < best) { best = score; bi = k; }
  }
  pb[(sl << 16) + n] = make_float2(best, __int_as_float(bi));
}

// ---------------- VQ finalize: merge, write e_t bf16, loss ----------------
__global__ __launch_bounds__(256) void k_vqf(
    const float* __restrict__ z3, const float* __restrict__ cb,
    const float2* __restrict__ pb, u16* __restrict__ et,
    float* __restrict__ acc) {
  int n = blockIdx.x * 256 + threadIdx.x;  // 65536
  float best = 3.4e38f; int bi = 0;
  #pragma unroll
  for (int s = 0; s < 4; ++s) {            // ascending slice + strict < = first argmin
    float2 c = pb[(s << 16) + n];
    if (c.x < best) { best = c.x; bi = __float_as_int(c.y); }
  }
  int b = n >> 10, hw = n & 1023;
  const float* zp = z3 + (b << 16) + hw;
  uint2* ep = (uint2*)(et + (n << 6));
  const float4* cq = (const float4*)(cb + (bi << 6));
  float lsum = 0.f;
  #pragma unroll
  for (int i = 0; i < 16; ++i) {
    float4 c = cq[i];
    float zv, df;
    zv = zp[(4*i+0) << 10]; df = c.x - zv; lsum = fmaf(df, df, lsum);
    zv = zp[(4*i+1) << 10]; df = c.y - zv; lsum = fmaf(df, df, lsum);
    zv = zp[(4*i+2) << 10]; df = c.z - zv; lsum = fmaf(df, df, lsum);
    zv = zp[(4*i+3) << 10]; df = c.w - zv; lsum = fmaf(df, df, lsum);
    ep[i] = make_uint2(f2bf(c.x) | ((unsigned)f2bf(c.y) << 16),
                       f2bf(c.z) | ((unsigned)f2bf(c.w) << 16));
  }
  __shared__ float red[256];
  red[threadIdx.x] = lsum; __syncthreads();
  #pragma unroll
  for (int s = 128; s > 0; s >>= 1) {
    if (threadIdx.x < s) red[threadIdx.x] += red[threadIdx.x + s];
    __syncthreads();
  }
  if (threadIdx.x == 0) atomicAdd(acc + 0, red[0]);
}

// ---------------- convT1: MFMA, block=(b,oh), waves=(pw2, xt2) ----------------
__global__ __launch_bounds__(256) void k_convT1(
    const u16* __restrict__ et, const u16* __restrict__ wf,
    const float* __restrict__ bias, u16* __restrict__ h1t) {
  int t = threadIdx.x;
  int lane = t & 63, wv = t >> 6;
  int n = lane & 15, q = lane >> 4;
  int oh = blockIdx.x & 63, b = blockIdx.x >> 6;   // grid 4096
  int ph = oh & 1, y = oh >> 1;
  int pw = wv >> 1, xt = wv & 1;
  int xA = xt * 16 + n;
  f32x4 acc[4] = {{0,0,0,0},{0,0,0,0},{0,0,0,0},{0,0,0,0}};
  int khs[2], dys[2], kws[2], dxs[2], nh, nw;
  if (ph) { nh = 2; khs[0] = 0; dys[0] = 1; khs[1] = 2; dys[1] = 0; }
  else    { nh = 1; khs[0] = 1; dys[0] = 0; }
  if (pw) { nw = 2; kws[0] = 0; dxs[0] = 1; kws[1] = 2; dxs[1] = 0; }
  else    { nw = 1; kws[0] = 1; dxs[0] = 0; }
  for (int a_ = 0; a_ < nh; ++a_) {
    int yy = y + dys[a_];
    bool yok = yy < 32;
    for (int c_ = 0; c_ < nw; ++c_) {
      int xx = xA + dxs[c_];
      bool ok = yok && (xx < 32);
      const u16* ap = et + (((b * 32 + yy) * 32 + xx) << 6) + q * 8;
      bf16x8 a0 = {}, a1 = {};
      if (ok) { a0 = *(const bf16x8*)ap; a1 = *(const bf16x8*)(ap + 32); }
      int kt = khs[a_] * 3 + kws[c_];
      const u16* wb = wf + (kt << 3) * 512 + lane * 8;   // [(kt*2+s)*4+nf]
      #pragma unroll
      for (int nf = 0; nf < 4; ++nf) {
        bf16x8 b0 = *(const bf16x8*)(wb + nf * 512);
        bf16x8 b1 = *(const bf16x8*)(wb + (4 + nf) * 512);
        acc[nf] = __builtin_amdgcn_mfma_f32_16x16x32_bf16(a0, b0, acc[nf], 0, 0, 0);
        acc[nf] = __builtin_amdgcn_mfma_f32_16x16x32_bf16(a1, b1, acc[nf], 0, 0, 0);
      }
    }
  }
  int xo = xt * 16 + (q << 2);
  u16* op = h1t + (((b * 64 + oh) * 64) << 6);
  #pragma unroll
  for (int nf = 0; nf < 4; ++nf) {
    float bv = bias[nf * 16 + n];
    #pragma unroll
    for (int r = 0; r < 4; ++r) {
      float v = fmaxf(acc[nf][r] + bv, 0.f);
      int ow = 2 * (xo + r) + pw;
      op[(ow << 6) + nf * 16 + n] = f2bf(v);
    }
  }
}

// ---------------- convT2: MFMA, block=(b,oh) 512thr, waves=(pw2, xt4) ----------------
__global__ __launch_bounds__(512) void k_convT2(
    const u16* __restrict__ h1t, const u16* __restrict__ wf,
    const float* __restrict__ bias, float* __restrict__ h2) {
  int t = threadIdx.x;
  int lane = t & 63, wv = t >> 6;                  // 8 waves
  int n = lane & 15, q = lane >> 4;
  int oh = blockIdx.x & 127, b = blockIdx.x >> 7;  // grid 8192
  int ph = oh & 1, y = oh >> 1;
  int pw = wv >> 2, xt = wv & 3;
  int xA = xt * 16 + n;
  f32x4 acc[2] = {{0,0,0,0},{0,0,0,0}};
  int khs[2], dys[2], kws[2], dxs[2], nh, nw;
  if (ph) { nh = 2; khs[0] = 0; dys[0] = 1; khs[1] = 2; dys[1] = 0; }
  else    { nh = 1; khs[0] = 1; dys[0] = 0; }
  if (pw) { nw = 2; kws[0] = 0; dxs[0] = 1; kws[1] = 2; dxs[1] = 0; }
  else    { nw = 1; kws[0] = 1; dxs[0] = 0; }
  for (int a_ = 0; a_ < nh; ++a_) {
    int yy = y + dys[a_];
    bool yok = yy < 64;
    for (int c_ = 0; c_ < nw; ++c_) {
      int xx = xA + dxs[c_];
      bool ok = yok && (xx < 64);
      const u16* ap = h1t + (((b * 64 + yy) * 64 + xx) << 6) + q * 8;
      bf16x8 a0 = {}, a1 = {};
      if (ok) { a0 = *(const bf16x8*)ap; a1 = *(const bf16x8*)(ap + 32); }
      int kt = khs[a_] * 3 + kws[c_];
      const u16* wb = wf + (kt << 2) * 512 + lane * 8;   // [(kt*2+s)*2+nf]
      #pragma unroll
      for (int nf = 0; nf < 2; ++nf) {
        bf16x8 b0 = *(const bf16x8*)(wb + nf * 512);
        bf16x8 b1 = *(const bf16x8*)(wb + (2 + nf) * 512);
        acc[nf] = __builtin_amdgcn_mfma_f32_16x16x32_bf16(a0, b0, acc[nf], 0, 0, 0);
        acc[nf] = __builtin_amdgcn_mfma_f32_16x16x32_bf16(a1, b1, acc[nf], 0, 0, 0);
      }
    }
  }
  int xo = xt * 16 + (q << 2);
  #pragma unroll
  for (int nf = 0; nf < 2; ++nf) {
    int co = nf * 16 + n;
    float bv = bias[co];
    #pragma unroll
    for (int r = 0; r < 4; ++r) {
      float v = fmaxf(acc[nf][r] + bv, 0.f);
      int ow = 2 * (xo + r) + pw;
      h2[(((b * 32 + co) * 128 + oh) << 7) + ow] = v;
    }
  }
}

// ---------------- convT3 + recon loss: fp32, 3co x 8ow/thread ----------------
__global__ __launch_bounds__(256, 4) void k_convT3(
    const float* __restrict__ in,   // h2 [64,32,128,128]
    const float* __restrict__ wt,   // wt3 [ci32][2][2][4]
    const float* __restrict__ bias, const float* __restrict__ x,
    float* __restrict__ xr, float* __restrict__ acc) {
  int t = threadIdx.x;
  int idx = blockIdx.x * 256 + t;    // 128000 exact
  int owg = idx & 15; int t2 = idx >> 4;
  int oh = t2 % 125; int b = t2 / 125;
  int ow0 = owg * 8;
  float b0 = bias[0], b1 = bias[1], b2 = bias[2];
  float a[3][8];
  #pragma unroll
  for (int s = 0; s < 8; ++s) { a[0][s] = b0; a[1][s] = b1; a[2][s] = b2; }
  const float* inb = in + (b << 19) + ow0;
  for (int ci = 0; ci < 32; ++ci) {
    #pragma unroll
    for (int kh = 0; kh < 2; ++kh) {
      const float* rp = inb + (ci << 14) + ((oh + 2 - kh) << 7);
      float4 qa = *(const float4*)rp;
      float4 qb = *(const float4*)(rp + 4);
      float2 qc = *(const float2*)(rp + 8);
      float v[10] = {qa.x, qa.y, qa.z, qa.w, qb.x, qb.y, qb.z, qb.w, qc.x, qc.y};
      #pragma unroll
      for (int kw = 0; kw < 2; ++kw) {
        float4 wv = *(const float4*)(wt + ((ci * 2 + kh) * 2 + kw) * 4);
        #pragma unroll
        for (int s = 0; s < 8; ++s) {
          float inv = v[s + 2 - kw];
          a[0][s] = fmaf(inv, wv.x, a[0][s]);
          a[1][s] = fmaf(inv, wv.y, a[1][s]);
          a[2][s] = fmaf(inv, wv.z, a[2][s]);
        }
      }
    }
  }
  int o = b * 46875 + oh * 125 + ow0;
  float lsum = 0.f;
  #pragma unroll
  for (int s = 0; s < 8; ++s) {
    if (ow0 + s < 125) {
      #pragma unroll
      for (int c = 0; c < 3; ++c) {
        float val = a[c][s];
        xr[o + s + c * 15625] = val;
        float d = val - x[o + s + c * 15625];
        lsum = fmaf(d, d, lsum);
      }
    }
  }
  __shared__ float red[256];
  red[t] = lsum; __syncthreads();
  #pragma unroll
  for (int s = 128; s > 0; s >>= 1) {
    if (t < s) red[t] += red[t + s];
    __syncthreads();
  }
  if (t == 0) atomicAdd(acc + 1, red[0]);
}

// ---------------- finalize ----------------
__global__ void k_fin(const float* __restrict__ acc, float* __restrict__ out) {
  if (threadIdx.x == 0 && blockIdx.x == 0) {
    float eq  = 1.25f * acc[0] / 4194304.0f;
    float rec = acc[1];
    out[0] = eq + rec;
    out[1] = eq;
    out[2] = rec;
  }
}

extern "C" void kernel_launch(void* const* d_in, const int* in_sizes, int n_in,
                              void* d_out, int out_size, void* d_ws, size_t ws_size,
                              hipStream_t stream) {
  (void)in_sizes; (void)n_in; (void)out_size; (void)ws_size;
  const float* x   = (const float*)d_in[0];
  const float* ew1 = (const float*)d_in[1];
  const float* eb1 = (const float*)d_in[2];
  const float* ew2 = (const float*)d_in[3];
  const float* eb2 = (const float*)d_in[4];
  const float* ew3 = (const float*)d_in[5];
  const float* eb3 = (const float*)d_in[6];
  const float* cb  = (const float*)d_in[7];
  const float* dw1 = (const float*)d_in[8];
  const float* db1 = (const float*)d_in[9];
  const float* dw2 = (const float*)d_in[10];
  const float* db2 = (const float*)d_in[11];
  const float* dw3 = (const float*)d_in[12];
  const float* db3 = (const float*)d_in[13];
  float* out = (float*)d_out;
  char*  ws  = (char*)d_ws;

  float*  acc  = (float*)(ws + 0);
  float*  c2   = (float*)(ws + 256);
  float*  wc1p = (float*)(ws + 4096);
  float*  wc3p = (float*)(ws + 8192);     // 16 KB
  float*  wt3  = (float*)(ws + 24576);
  u16*    w2f  = (u16*)  (ws + 32768);    // 36 KB
  u16*    wt1f = (u16*)  (ws + 69632);    // 72 KB
  u16*    wt2f = (u16*)  (ws + 143360);   // 36 KB
  // Lifetimes: z1t dead after conv2; z2 after conv3; z3/pb after vqf;
  // e_t after convT1; h1t (reuses z1t/z2 region) after convT2; h2 to convT3.
  u16*    z1t  = (u16*)  (ws + 1048576);  // 16515072 B
  float*  z2   = (float*)(ws + 18874368); // 16777216 B
  float*  z3   = (float*)(ws + 35651584); // 16777216 B
  float2* pb   = (float2*)(ws + 52428800);//  2097152 B
  u16*    et   = (u16*)  (ws + 54525952); //  8388608 B
  u16*    h1t  = (u16*)  (ws + 1048576);  // 33030144 B (over dead z1t/z2)
  float*  h2   = (float*)(ws + 67108864); // 134217728 B -> ends 201326592

  hipMemsetAsync(acc, 0, 64, stream);
  k_prep  <<<312,  256, 0, stream>>>(ew1, ew2, ew3, dw1, dw2, dw3, cb,
                                     wc1p, wc3p, wt3, c2, w2f, wt1f, wt2f);
  k_conv1 <<<1024, 256, 0, stream>>>(x, wc1p, eb1, z1t);
  k_conv2 <<<2048, 256, 0, stream>>>(z1t, w2f, eb2, z2);
  k_conv3 <<<512,  256, 0, stream>>>(z2, wc3p, eb3, z3);
  k_vqp   <<<1024, 256, 0, stream>>>(z3, cb, c2, pb);
  k_vqf   <<<256,  256, 0, stream>>>(z3, cb, pb, et, acc);
  k_convT1<<<4096, 256, 0, stream>>>(et, wt1f, db1, h1t);
  k_convT2<<<8192, 512, 0, stream>>>(h1t, wt2f, db2, h2);
  k_convT3<<<500,  256, 0, stream>>>(h2, wt3, db3, x, out + 3, acc);
  k_fin   <<<1,    64,  0, stream>>>(acc, out);
}